// Round 6
// baseline (438.699 us; speedup 1.0000x reference)
//
#include <hip/hip_runtime.h>
#include <hip/hip_bf16.h>
#include <hip/hip_fp16.h>

#define Nn 50000
#define RR 3
#define EE 300000

typedef __attribute__((ext_vector_type(8))) short short8;
typedef __attribute__((ext_vector_type(4))) short short4v;
typedef __attribute__((ext_vector_type(4))) float floatx4;

__device__ __forceinline__ short f2bf(float f) {
    __hip_bfloat16 h = __float2bfloat16(f);
    return *reinterpret_cast<short*>(&h);
}

// ---------------- CSR build ----------------

__global__ void zero_kernel(int* counts, int* totals) {
    int i = blockIdx.x * blockDim.x + threadIdx.x;
    if (i < RR * Nn) counts[i] = 0;
    if (i < 4) totals[i] = 0;
}

__global__ void count_kernel(const int* edges, int* counts) {
    int i = blockIdx.x * blockDim.x + threadIdx.x;
    if (i >= RR * EE) return;
    int r = i / EE, e = i - r * EE;
    int dst = edges[(size_t)r * 2 * EE + EE + e];
    atomicAdd(&counts[r * Nn + dst], 1);
}

__global__ __launch_bounds__(256) void alloc_kernel(const int* __restrict__ counts,
                                                    int* __restrict__ row_start,
                                                    int* __restrict__ cursor,
                                                    int* __restrict__ totals) {
    __shared__ int s[256];
    __shared__ int base_s;
    int r = blockIdx.y;
    int tid = threadIdx.x;
    int n = blockIdx.x * 256 + tid;
    int idx = r * Nn + n;
    int c = (n < Nn) ? counts[idx] : 0;
    s[tid] = c;
    __syncthreads();
    #pragma unroll
    for (int off = 1; off < 256; off <<= 1) {
        int v = 0;
        if (tid >= off) v = s[tid - off];
        __syncthreads();
        if (tid >= off) s[tid] += v;
        __syncthreads();
    }
    if (tid == 255) base_s = atomicAdd(&totals[r], s[255]);
    __syncthreads();
    if (n < Nn) {
        int st = base_s + s[tid] - c;
        row_start[idx] = st;
        cursor[idx] = st;
    }
}

__global__ void scatter_kernel(const int* edges, int* cursor, int2* csr) {
    int i = blockIdx.x * blockDim.x + threadIdx.x;
    if (i >= RR * EE) return;
    int r = i / EE, e = i - r * EE;
    int src = edges[(size_t)r * 2 * EE + e];
    int dst = edges[(size_t)r * 2 * EE + EE + e];
    int slot = atomicAdd(&cursor[r * Nn + dst], 1);
    csr[(size_t)r * EE + slot] = make_int2(src, dst);
}

// ---------------- W pre-swizzle into MFMA B-fragment layout ----------------

__global__ void wswz_kernel(const float* __restrict__ W1, const float* __restrict__ W2,
                            short* __restrict__ Z) {
    int idx = blockIdx.x * 256 + threadIdx.x;   // 2 layers * 3r * 4kt * 8nt * 64 lanes = 12288
    if (idx >= 12288) return;
    int lane = idx & 63;
    int nt = (idx >> 6) & 7;
    int kt = (idx >> 9) & 3;
    int rl = idx >> 11;
    int layer = rl / 3, r = rl % 3;
    const float* W = (layer ? W2 : W1) + (size_t)r * 16384;
    int n = nt * 16 + (lane & 15);
    int k0 = kt * 32 + (lane >> 4) * 8;
    short8 v;
    #pragma unroll
    for (int j = 0; j < 8; ++j) v[j] = f2bf(W[(size_t)(k0 + j) * 128 + n]);
    *(short8*)&Z[(size_t)idx * 8] = v;
}

// ---------------- MFMA GEMM: A[N,128] @ W[r][128,128] -> feat[r][N][128] fp16 ----------------

template<bool RELU_A>
__global__ __launch_bounds__(256) void gemm_proj_mfma(const float* __restrict__ A,
                                                      const short* __restrict__ Z,
                                                      __half* __restrict__ C) {
    __shared__ short A_lds[64 * 136];
    int tid = threadIdx.x;
    int row0 = blockIdx.x * 64;
    #pragma unroll
    for (int p = 0; p < 8; ++p) {
        int f = p * 256 + tid;
        int row = f >> 5;
        int c4 = (f & 31) * 4;
        float4 v = make_float4(0.f, 0.f, 0.f, 0.f);
        if (row0 + row < Nn) v = *(const float4*)&A[(size_t)(row0 + row) * 128 + c4];
        if (RELU_A) {
            v.x = fmaxf(v.x, 0.f); v.y = fmaxf(v.y, 0.f);
            v.z = fmaxf(v.z, 0.f); v.w = fmaxf(v.w, 0.f);
        }
        short4v sv;
        sv[0] = f2bf(v.x); sv[1] = f2bf(v.y); sv[2] = f2bf(v.z); sv[3] = f2bf(v.w);
        *(short4v*)&A_lds[row * 136 + c4] = sv;
    }
    __syncthreads();
    int wave = tid >> 6, lane = tid & 63;
    int m = lane & 15, q = lane >> 4;
    short8 af[4];
    #pragma unroll
    for (int kt = 0; kt < 4; ++kt)
        af[kt] = *(short8*)&A_lds[(wave * 16 + m) * 136 + kt * 32 + q * 8];
    for (int r = 0; r < RR; ++r) {
        floatx4 acc[8];
        #pragma unroll
        for (int nt = 0; nt < 8; ++nt) acc[nt] = (floatx4)(0.f);
        const short* Zr = Z + (size_t)r * 16384;
        #pragma unroll
        for (int kt = 0; kt < 4; ++kt) {
            #pragma unroll
            for (int nt = 0; nt < 8; ++nt) {
                short8 bf = *(const short8*)&Zr[(size_t)(kt * 8 + nt) * 512 + lane * 8];
                acc[nt] = __builtin_amdgcn_mfma_f32_16x16x32_bf16(af[kt], bf, acc[nt], 0, 0, 0);
            }
        }
        __half* Cr = C + (size_t)r * Nn * 128;
        #pragma unroll
        for (int nt = 0; nt < 8; ++nt) {
            int col = nt * 16 + m;
            #pragma unroll
            for (int reg = 0; reg < 4; ++reg) {
                int row = row0 + wave * 16 + q * 4 + reg;
                if (row < Nn) Cr[(size_t)row * 128 + col] = __float2half(acc[nt][reg]);
            }
        }
    }
}

// ---------------- Final GEMM: A[N,128] @ Wl[128,64] + bl -> out [N,64] fp32 ----------------

__global__ __launch_bounds__(256) void gemm_final_kernel(const float* __restrict__ A,
                                                         const float* __restrict__ Wl,
                                                         const float* __restrict__ bl,
                                                         float* __restrict__ out) {
    __shared__ float As[16][65];
    __shared__ float Bs[16][65];
    int tid = threadIdx.x;
    int row0 = blockIdx.x * 64;
    float acc[4][4] = {};
    int tx = tid & 15, ty = tid >> 4;
    for (int k0 = 0; k0 < 128; k0 += 16) {
        {
            int mm = tid >> 2, c = (tid & 3) * 4;
            int row = row0 + mm;
            float4 v = make_float4(0.f, 0.f, 0.f, 0.f);
            if (row < Nn) v = *(const float4*)&A[(size_t)row * 128 + k0 + c];
            As[c + 0][mm] = v.x; As[c + 1][mm] = v.y; As[c + 2][mm] = v.z; As[c + 3][mm] = v.w;
        }
        {
            int kk = tid >> 4, j = (tid & 15) * 4;
            float4 v = *(const float4*)&Wl[(size_t)(k0 + kk) * 64 + j];
            *(float4*)&Bs[kk][j] = v;
        }
        __syncthreads();
        #pragma unroll
        for (int kk = 0; kk < 16; ++kk) {
            float4 a = *(const float4*)&As[kk][ty * 4];
            float4 b = *(const float4*)&Bs[kk][tx * 4];
            float av[4] = {a.x, a.y, a.z, a.w};
            float bv[4] = {b.x, b.y, b.z, b.w};
            #pragma unroll
            for (int i = 0; i < 4; ++i)
                #pragma unroll
                for (int j = 0; j < 4; ++j) acc[i][j] += av[i] * bv[j];
        }
        __syncthreads();
    }
    float4 bias = *(const float4*)&bl[tx * 4];
    #pragma unroll
    for (int i = 0; i < 4; ++i) {
        int row = row0 + ty * 4 + i;
        if (row >= Nn) continue;
        float4 v = make_float4(acc[i][0] + bias.x, acc[i][1] + bias.y,
                               acc[i][2] + bias.z, acc[i][3] + bias.w);
        *(float4*)&out[(size_t)row * 64 + tx * 4] = v;
    }
}

// ---------------- el/er from fp16 feat ----------------

__global__ void elr_kernel(const __half2* __restrict__ feat2, const float* __restrict__ al,
                           const float* __restrict__ ar, float* __restrict__ el,
                           float* __restrict__ er) {
    int i = blockIdx.x * blockDim.x + threadIdx.x;
    if (i >= RR * Nn * 4) return;
    int h = i & 3;
    int nr = i >> 2;
    int n = nr % Nn;
    int r = nr / Nn;
    const __half2* f = feat2 + ((size_t)(r * Nn + n) * 64 + h * 16);
    const float* alp = al + r * 128 + h * 32;
    const float* arp = ar + r * 128 + h * 32;
    float sl = 0.f, sr = 0.f;
    #pragma unroll
    for (int d = 0; d < 16; ++d) {
        float2 v = __half22float2(f[d]);
        sl += v.x * alp[2 * d] + v.y * alp[2 * d + 1];
        sr += v.x * arp[2 * d] + v.y * arp[2 * d + 1];
    }
    el[i] = sl;
    er[i] = sr;
}

// ---------------- edge-parallel softmax weights: wq[h][r*EE+k] = exp(leaky(el[src]+er[dst])) --------

__global__ __launch_bounds__(256) void wexp_kernel(const int2* __restrict__ csr,
                                                   const float* __restrict__ el,
                                                   const float* __restrict__ er,
                                                   float* __restrict__ wq) {
    int r = blockIdx.y;
    int k = blockIdx.x * 256 + threadIdx.x;
    if (k >= EE) return;
    size_t gk = (size_t)r * EE + k;
    int2 e = csr[gk];
    float4 l4 = *(const float4*)&el[(size_t)(r * Nn + e.x) * 4];
    float4 r4 = *(const float4*)&er[(size_t)(r * Nn + e.y) * 4];
    float lv[4] = {l4.x, l4.y, l4.z, l4.w};
    float rv[4] = {r4.x, r4.y, r4.z, r4.w};
    #pragma unroll
    for (int h = 0; h < 4; ++h) {
        float x = lv[h] + rv[h];
        x = (x > 0.f) ? x : 0.2f * x;
        wq[(size_t)h * (RR * EE) + gk] = __expf(x);
    }
}

// ---------------- aggregation: one wave per dst node; weights precomputed ----------------
// exp(e)/sum(exp(e)) == softmax (no-max form); |e| <~ 1.5 here so no overflow risk.

__global__ __launch_bounds__(256) void agg_kernel(const __half2* __restrict__ feat2,
                                                  const float* __restrict__ wq,
                                                  const int2* __restrict__ csr,
                                                  const int* __restrict__ row_start,
                                                  const int* __restrict__ counts,
                                                  const float* __restrict__ b,
                                                  float* __restrict__ out) {
    int wave = threadIdx.x >> 6;
    int lane = threadIdx.x & 63;
    int n = blockIdx.x * 4 + wave;
    if (n >= Nn) return;
    int h = lane >> 4;        // head for this lane's d-pair
    int hl = lane & 15;
    int grp = lane & 48;
    int t2 = lane * 2;
    float accx = b[t2] + b[128 + t2] + b[256 + t2];
    float accy = b[t2 + 1] + b[128 + t2 + 1] + b[256 + t2 + 1];
    for (int r = 0; r < RR; ++r) {
        int base = r * Nn + n;
        int cnt = counts[base];
        if (cnt == 0) continue;
        int start = row_start[base];
        const int2* ce = csr + (size_t)r * EE;
        const float* wp = wq + (size_t)h * (RR * EE) + (size_t)r * EE;
        const __half2* fr = feat2 + (size_t)r * Nn * 64;
        float den = 0.f, numx = 0.f, numy = 0.f;
        for (int i0 = 0; i0 < cnt; i0 += 16) {
            int s_l = 0; float w_l = 0.f;
            if (i0 + hl < cnt) {
                int idx = start + i0 + hl;
                s_l = ce[idx].x;
                w_l = wp[idx];
            }
            int mm = cnt - i0; if (mm > 16) mm = 16;
            int j = 0;
            for (; j + 3 < mm; j += 4) {
                int s0 = __shfl(s_l, j);
                int s1 = __shfl(s_l, j + 1);
                int s2 = __shfl(s_l, j + 2);
                int s3 = __shfl(s_l, j + 3);
                float w0 = __shfl(w_l, grp | j);
                float w1 = __shfl(w_l, grp | (j + 1));
                float w2 = __shfl(w_l, grp | (j + 2));
                float w3 = __shfl(w_l, grp | (j + 3));
                __half2 f0 = fr[(size_t)s0 * 64 + lane];
                __half2 f1 = fr[(size_t)s1 * 64 + lane];
                __half2 f2 = fr[(size_t)s2 * 64 + lane];
                __half2 f3 = fr[(size_t)s3 * 64 + lane];
                float2 g0 = __half22float2(f0), g1 = __half22float2(f1);
                float2 g2 = __half22float2(f2), g3 = __half22float2(f3);
                den += (w0 + w1) + (w2 + w3);
                numx += w0 * g0.x + w1 * g1.x + w2 * g2.x + w3 * g3.x;
                numy += w0 * g0.y + w1 * g1.y + w2 * g2.y + w3 * g3.y;
            }
            for (; j < mm; ++j) {
                int s0 = __shfl(s_l, j);
                float w0 = __shfl(w_l, grp | j);
                __half2 f0 = fr[(size_t)s0 * 64 + lane];
                float2 g0 = __half22float2(f0);
                den += w0; numx += w0 * g0.x; numy += w0 * g0.y;
            }
        }
        float inv = 1.f / den;
        accx += numx * inv;
        accy += numy * inv;
    }
    *(float2*)&out[(size_t)n * 128 + t2] = make_float2(accx, accy);
}

// ---------------- launch ----------------

extern "C" void kernel_launch(void* const* d_in, const int* in_sizes, int n_in,
                              void* d_out, int out_size, void* d_ws, size_t ws_size,
                              hipStream_t stream) {
    const float* x   = (const float*)d_in[0];
    const int*  edges = (const int*)d_in[1];
    const float* W1  = (const float*)d_in[2];
    const float* al1 = (const float*)d_in[3];
    const float* ar1 = (const float*)d_in[4];
    const float* b1  = (const float*)d_in[5];
    const float* W2  = (const float*)d_in[6];
    const float* al2 = (const float*)d_in[7];
    const float* ar2 = (const float*)d_in[8];
    const float* b2  = (const float*)d_in[9];
    const float* Wl  = (const float*)d_in[10];
    const float* bl  = (const float*)d_in[11];
    float* out = (float*)d_out;

    // workspace layout (~92 MB; ws proven >= 113 MB in R2)
    __half* feat  = (__half*)d_ws;                          // 3*N*128 fp16
    short* Z      = (short*)(feat + (size_t)RR * Nn * 128); // 98304 bf16
    float* el     = (float*)(Z + 98304);                    // 3*N*4
    float* er     = el + (size_t)RR * Nn * 4;               // 3*N*4
    float* outbuf = er + (size_t)RR * Nn * 4;               // N*128 fp32
    float* wq     = outbuf + (size_t)Nn * 128;              // 4 * 3E floats (head-major planes)
    int* counts    = (int*)(wq + (size_t)4 * RR * EE);      // 3*N
    int* row_start = counts + RR * Nn;                      // 3*N
    int* cursor    = row_start + RR * Nn;                   // 3*N
    int* totals    = cursor + RR * Nn;                      // 4
    int2* csr      = (int2*)(totals + 4);                   // 3*E int2 {src,dst}

    const int rowBlocks  = (Nn + 63) / 64;    // 782
    const int nodeBlocks = (Nn + 255) / 256;  // 196
    const int aggBlocks  = (Nn + 3) / 4;      // 12500
    const int edgeBlocks = (EE + 255) / 256;  // 1172

    // weight swizzle + CSR build
    wswz_kernel<<<48, 256, 0, stream>>>(W1, W2, Z);
    zero_kernel<<<(RR * Nn + 255) / 256, 256, 0, stream>>>(counts, totals);
    count_kernel<<<(RR * EE + 255) / 256, 256, 0, stream>>>(edges, counts);
    alloc_kernel<<<dim3(nodeBlocks, RR), 256, 0, stream>>>(counts, row_start, cursor, totals);
    scatter_kernel<<<(RR * EE + 255) / 256, 256, 0, stream>>>(edges, cursor, csr);

    // layer 1
    gemm_proj_mfma<false><<<rowBlocks, 256, 0, stream>>>(x, Z, feat);
    elr_kernel<<<(RR * Nn * 4 + 255) / 256, 256, 0, stream>>>((const __half2*)feat, al1, ar1, el, er);
    wexp_kernel<<<dim3(edgeBlocks, RR), 256, 0, stream>>>(csr, el, er, wq);
    agg_kernel<<<aggBlocks, 256, 0, stream>>>((const __half2*)feat, wq, csr, row_start, counts, b1, outbuf);

    // layer 2 (relu fused into A-stage)
    gemm_proj_mfma<true><<<rowBlocks, 256, 0, stream>>>(outbuf, Z + 49152, feat);
    elr_kernel<<<(RR * Nn * 4 + 255) / 256, 256, 0, stream>>>((const __half2*)feat, al2, ar2, el, er);
    wexp_kernel<<<dim3(edgeBlocks, RR), 256, 0, stream>>>(csr, el, er, wq);
    agg_kernel<<<aggBlocks, 256, 0, stream>>>((const __half2*)feat, wq, csr, row_start, counts, b2, outbuf);

    // final linear
    gemm_final_kernel<<<rowBlocks, 256, 0, stream>>>(outbuf, Wl, bl, out);
}

// Round 7
// 397.660 us; speedup vs baseline: 1.1032x; 1.1032x over previous
//
#include <hip/hip_runtime.h>
#include <hip/hip_bf16.h>
#include <hip/hip_fp16.h>

#define Nn 50000
#define RR 3
#define EE 300000

typedef __attribute__((ext_vector_type(8))) short short8;
typedef __attribute__((ext_vector_type(4))) short short4v;
typedef __attribute__((ext_vector_type(4))) float floatx4;

__device__ __forceinline__ short f2bf(float f) {
    __hip_bfloat16 h = __float2bfloat16(f);
    return *reinterpret_cast<short*>(&h);
}

// ---------------- CSR build ----------------

__global__ void zero_kernel(int* counts, int* totals) {
    int i = blockIdx.x * blockDim.x + threadIdx.x;
    if (i < RR * Nn) counts[i] = 0;
    if (i < 4) totals[i] = 0;
}

// 4 edges per thread (int4 loads); atomic returns the within-dst ordinal -> ord.
__global__ void count_kernel(const int* __restrict__ edges, int* __restrict__ counts,
                             int* __restrict__ ord) {
    int i = blockIdx.x * blockDim.x + threadIdx.x;   // RR*EE/4 threads
    if (i >= RR * EE / 4) return;
    int g = i * 4;
    int r = g / EE, e0 = g - r * EE;
    int4 d = *(const int4*)&edges[(size_t)r * 2 * EE + EE + e0];
    int* cb = counts + r * Nn;
    int4 o;
    o.x = atomicAdd(&cb[d.x], 1);
    o.y = atomicAdd(&cb[d.y], 1);
    o.z = atomicAdd(&cb[d.z], 1);
    o.w = atomicAdd(&cb[d.w], 1);
    *(int4*)&ord[g] = o;
}

__global__ __launch_bounds__(256) void alloc_kernel(const int* __restrict__ counts,
                                                    int* __restrict__ row_start,
                                                    int* __restrict__ totals) {
    __shared__ int s[256];
    __shared__ int base_s;
    int r = blockIdx.y;
    int tid = threadIdx.x;
    int n = blockIdx.x * 256 + tid;
    int idx = r * Nn + n;
    int c = (n < Nn) ? counts[idx] : 0;
    s[tid] = c;
    __syncthreads();
    #pragma unroll
    for (int off = 1; off < 256; off <<= 1) {
        int v = 0;
        if (tid >= off) v = s[tid - off];
        __syncthreads();
        if (tid >= off) s[tid] += v;
        __syncthreads();
    }
    if (tid == 255) base_s = atomicAdd(&totals[r], s[255]);
    __syncthreads();
    if (n < Nn) row_start[idx] = base_s + s[tid] - c;
}

// No atomics: slot = row_start[dst] + ord[edge]. 4 independent edges per thread.
__global__ void scatter_kernel(const int* __restrict__ edges, const int* __restrict__ ord,
                               const int* __restrict__ row_start, int2* __restrict__ csr) {
    int i = blockIdx.x * blockDim.x + threadIdx.x;
    if (i >= RR * EE / 4) return;
    int g = i * 4;
    int r = g / EE, e0 = g - r * EE;
    int4 s4 = *(const int4*)&edges[(size_t)r * 2 * EE + e0];
    int4 d4 = *(const int4*)&edges[(size_t)r * 2 * EE + EE + e0];
    int4 o4 = *(const int4*)&ord[g];
    const int* rs = row_start + r * Nn;
    int2* cb = csr + (size_t)r * EE;
    cb[rs[d4.x] + o4.x] = make_int2(s4.x, d4.x);
    cb[rs[d4.y] + o4.y] = make_int2(s4.y, d4.y);
    cb[rs[d4.z] + o4.z] = make_int2(s4.z, d4.z);
    cb[rs[d4.w] + o4.w] = make_int2(s4.w, d4.w);
}

// ---------------- W pre-swizzle into MFMA B-fragment layout ----------------

__global__ void wswz_kernel(const float* __restrict__ W1, const float* __restrict__ W2,
                            short* __restrict__ Z) {
    int idx = blockIdx.x * 256 + threadIdx.x;   // 2 layers * 3r * 4kt * 8nt * 64 lanes = 12288
    if (idx >= 12288) return;
    int lane = idx & 63;
    int nt = (idx >> 6) & 7;
    int kt = (idx >> 9) & 3;
    int rl = idx >> 11;
    int layer = rl / 3, r = rl % 3;
    const float* W = (layer ? W2 : W1) + (size_t)r * 16384;
    int n = nt * 16 + (lane & 15);
    int k0 = kt * 32 + (lane >> 4) * 8;
    short8 v;
    #pragma unroll
    for (int j = 0; j < 8; ++j) v[j] = f2bf(W[(size_t)(k0 + j) * 128 + n]);
    *(short8*)&Z[(size_t)idx * 8] = v;
}

// ---------------- MFMA GEMM: A[N,128] @ W[r][128,128] -> feat[r][N][128] fp16 ----------------

template<bool RELU_A>
__global__ __launch_bounds__(256) void gemm_proj_mfma(const float* __restrict__ A,
                                                      const short* __restrict__ Z,
                                                      __half* __restrict__ C) {
    __shared__ short A_lds[64 * 136];
    int tid = threadIdx.x;
    int row0 = blockIdx.x * 64;
    #pragma unroll
    for (int p = 0; p < 8; ++p) {
        int f = p * 256 + tid;
        int row = f >> 5;
        int c4 = (f & 31) * 4;
        float4 v = make_float4(0.f, 0.f, 0.f, 0.f);
        if (row0 + row < Nn) v = *(const float4*)&A[(size_t)(row0 + row) * 128 + c4];
        if (RELU_A) {
            v.x = fmaxf(v.x, 0.f); v.y = fmaxf(v.y, 0.f);
            v.z = fmaxf(v.z, 0.f); v.w = fmaxf(v.w, 0.f);
        }
        short4v sv;
        sv[0] = f2bf(v.x); sv[1] = f2bf(v.y); sv[2] = f2bf(v.z); sv[3] = f2bf(v.w);
        *(short4v*)&A_lds[row * 136 + c4] = sv;
    }
    __syncthreads();
    int wave = tid >> 6, lane = tid & 63;
    int m = lane & 15, q = lane >> 4;
    short8 af[4];
    #pragma unroll
    for (int kt = 0; kt < 4; ++kt)
        af[kt] = *(short8*)&A_lds[(wave * 16 + m) * 136 + kt * 32 + q * 8];
    for (int r = 0; r < RR; ++r) {
        floatx4 acc[8];
        #pragma unroll
        for (int nt = 0; nt < 8; ++nt) acc[nt] = (floatx4)(0.f);
        const short* Zr = Z + (size_t)r * 16384;
        #pragma unroll
        for (int kt = 0; kt < 4; ++kt) {
            #pragma unroll
            for (int nt = 0; nt < 8; ++nt) {
                short8 bf = *(const short8*)&Zr[(size_t)(kt * 8 + nt) * 512 + lane * 8];
                acc[nt] = __builtin_amdgcn_mfma_f32_16x16x32_bf16(af[kt], bf, acc[nt], 0, 0, 0);
            }
        }
        __half* Cr = C + (size_t)r * Nn * 128;
        #pragma unroll
        for (int nt = 0; nt < 8; ++nt) {
            int col = nt * 16 + m;
            #pragma unroll
            for (int reg = 0; reg < 4; ++reg) {
                int row = row0 + wave * 16 + q * 4 + reg;
                if (row < Nn) Cr[(size_t)row * 128 + col] = __float2half(acc[nt][reg]);
            }
        }
    }
}

// ---------------- Final GEMM: A[N,128] @ Wl[128,64] + bl -> out [N,64] fp32 ----------------

__global__ __launch_bounds__(256) void gemm_final_kernel(const float* __restrict__ A,
                                                         const float* __restrict__ Wl,
                                                         const float* __restrict__ bl,
                                                         float* __restrict__ out) {
    __shared__ float As[16][65];
    __shared__ float Bs[16][65];
    int tid = threadIdx.x;
    int row0 = blockIdx.x * 64;
    float acc[4][4] = {};
    int tx = tid & 15, ty = tid >> 4;
    for (int k0 = 0; k0 < 128; k0 += 16) {
        {
            int mm = tid >> 2, c = (tid & 3) * 4;
            int row = row0 + mm;
            float4 v = make_float4(0.f, 0.f, 0.f, 0.f);
            if (row < Nn) v = *(const float4*)&A[(size_t)row * 128 + k0 + c];
            As[c + 0][mm] = v.x; As[c + 1][mm] = v.y; As[c + 2][mm] = v.z; As[c + 3][mm] = v.w;
        }
        {
            int kk = tid >> 4, j = (tid & 15) * 4;
            float4 v = *(const float4*)&Wl[(size_t)(k0 + kk) * 64 + j];
            *(float4*)&Bs[kk][j] = v;
        }
        __syncthreads();
        #pragma unroll
        for (int kk = 0; kk < 16; ++kk) {
            float4 a = *(const float4*)&As[kk][ty * 4];
            float4 b = *(const float4*)&Bs[kk][tx * 4];
            float av[4] = {a.x, a.y, a.z, a.w};
            float bv[4] = {b.x, b.y, b.z, b.w};
            #pragma unroll
            for (int i = 0; i < 4; ++i)
                #pragma unroll
                for (int j = 0; j < 4; ++j) acc[i][j] += av[i] * bv[j];
        }
        __syncthreads();
    }
    float4 bias = *(const float4*)&bl[tx * 4];
    #pragma unroll
    for (int i = 0; i < 4; ++i) {
        int row = row0 + ty * 4 + i;
        if (row >= Nn) continue;
        float4 v = make_float4(acc[i][0] + bias.x, acc[i][1] + bias.y,
                               acc[i][2] + bias.z, acc[i][3] + bias.w);
        *(float4*)&out[(size_t)row * 64 + tx * 4] = v;
    }
}

// ---------------- el/er from fp16 feat ----------------

__global__ void elr_kernel(const __half2* __restrict__ feat2, const float* __restrict__ al,
                           const float* __restrict__ ar, float* __restrict__ el,
                           float* __restrict__ er) {
    int i = blockIdx.x * blockDim.x + threadIdx.x;
    if (i >= RR * Nn * 4) return;
    int h = i & 3;
    int nr = i >> 2;
    int n = nr % Nn;
    int r = nr / Nn;
    const __half2* f = feat2 + ((size_t)(r * Nn + n) * 64 + h * 16);
    const float* alp = al + r * 128 + h * 32;
    const float* arp = ar + r * 128 + h * 32;
    float sl = 0.f, sr = 0.f;
    #pragma unroll
    for (int d = 0; d < 16; ++d) {
        float2 v = __half22float2(f[d]);
        sl += v.x * alp[2 * d] + v.y * alp[2 * d + 1];
        sr += v.x * arp[2 * d] + v.y * arp[2 * d + 1];
    }
    el[i] = sl;
    er[i] = sr;
}

// ---------------- edge-parallel softmax weights: wq[h][r*EE+k] = exp(leaky(el[src]+er[dst])) --------

__global__ __launch_bounds__(256) void wexp_kernel(const int2* __restrict__ csr,
                                                   const float* __restrict__ el,
                                                   const float* __restrict__ er,
                                                   float* __restrict__ wq) {
    int r = blockIdx.y;
    int k = blockIdx.x * 256 + threadIdx.x;
    if (k >= EE) return;
    size_t gk = (size_t)r * EE + k;
    int2 e = csr[gk];
    float4 l4 = *(const float4*)&el[(size_t)(r * Nn + e.x) * 4];
    float4 r4 = *(const float4*)&er[(size_t)(r * Nn + e.y) * 4];
    float lv[4] = {l4.x, l4.y, l4.z, l4.w};
    float rv[4] = {r4.x, r4.y, r4.z, r4.w};
    #pragma unroll
    for (int h = 0; h < 4; ++h) {
        float x = lv[h] + rv[h];
        x = (x > 0.f) ? x : 0.2f * x;
        wq[(size_t)h * (RR * EE) + gk] = __expf(x);
    }
}

// ---------------- aggregation: one wave per dst node; weights precomputed ----------------

__global__ __launch_bounds__(256) void agg_kernel(const __half2* __restrict__ feat2,
                                                  const float* __restrict__ wq,
                                                  const int2* __restrict__ csr,
                                                  const int* __restrict__ row_start,
                                                  const int* __restrict__ counts,
                                                  const float* __restrict__ b,
                                                  float* __restrict__ out) {
    int wave = threadIdx.x >> 6;
    int lane = threadIdx.x & 63;
    int n = blockIdx.x * 4 + wave;
    if (n >= Nn) return;
    int h = lane >> 4;
    int hl = lane & 15;
    int grp = lane & 48;
    int t2 = lane * 2;
    float accx = b[t2] + b[128 + t2] + b[256 + t2];
    float accy = b[t2 + 1] + b[128 + t2 + 1] + b[256 + t2 + 1];
    for (int r = 0; r < RR; ++r) {
        int base = r * Nn + n;
        int cnt = counts[base];
        if (cnt == 0) continue;
        int start = row_start[base];
        const int2* ce = csr + (size_t)r * EE;
        const float* wp = wq + (size_t)h * (RR * EE) + (size_t)r * EE;
        const __half2* fr = feat2 + (size_t)r * Nn * 64;
        float den = 0.f, numx = 0.f, numy = 0.f;
        for (int i0 = 0; i0 < cnt; i0 += 16) {
            int s_l = 0; float w_l = 0.f;
            if (i0 + hl < cnt) {
                int idx = start + i0 + hl;
                s_l = ce[idx].x;
                w_l = wp[idx];
            }
            int mm = cnt - i0; if (mm > 16) mm = 16;
            int j = 0;
            for (; j + 3 < mm; j += 4) {
                int s0 = __shfl(s_l, j);
                int s1 = __shfl(s_l, j + 1);
                int s2 = __shfl(s_l, j + 2);
                int s3 = __shfl(s_l, j + 3);
                float w0 = __shfl(w_l, grp | j);
                float w1 = __shfl(w_l, grp | (j + 1));
                float w2 = __shfl(w_l, grp | (j + 2));
                float w3 = __shfl(w_l, grp | (j + 3));
                __half2 f0 = fr[(size_t)s0 * 64 + lane];
                __half2 f1 = fr[(size_t)s1 * 64 + lane];
                __half2 f2 = fr[(size_t)s2 * 64 + lane];
                __half2 f3 = fr[(size_t)s3 * 64 + lane];
                float2 g0 = __half22float2(f0), g1 = __half22float2(f1);
                float2 g2 = __half22float2(f2), g3 = __half22float2(f3);
                den += (w0 + w1) + (w2 + w3);
                numx += w0 * g0.x + w1 * g1.x + w2 * g2.x + w3 * g3.x;
                numy += w0 * g0.y + w1 * g1.y + w2 * g2.y + w3 * g3.y;
            }
            for (; j < mm; ++j) {
                int s0 = __shfl(s_l, j);
                float w0 = __shfl(w_l, grp | j);
                __half2 f0 = fr[(size_t)s0 * 64 + lane];
                float2 g0 = __half22float2(f0);
                den += w0; numx += w0 * g0.x; numy += w0 * g0.y;
            }
        }
        float inv = 1.f / den;
        accx += numx * inv;
        accy += numy * inv;
    }
    *(float2*)&out[(size_t)n * 128 + t2] = make_float2(accx, accy);
}

// ---------------- launch ----------------

extern "C" void kernel_launch(void* const* d_in, const int* in_sizes, int n_in,
                              void* d_out, int out_size, void* d_ws, size_t ws_size,
                              hipStream_t stream) {
    const float* x   = (const float*)d_in[0];
    const int*  edges = (const int*)d_in[1];
    const float* W1  = (const float*)d_in[2];
    const float* al1 = (const float*)d_in[3];
    const float* ar1 = (const float*)d_in[4];
    const float* b1  = (const float*)d_in[5];
    const float* W2  = (const float*)d_in[6];
    const float* al2 = (const float*)d_in[7];
    const float* ar2 = (const float*)d_in[8];
    const float* b2  = (const float*)d_in[9];
    const float* Wl  = (const float*)d_in[10];
    const float* bl  = (const float*)d_in[11];
    float* out = (float*)d_out;

    // workspace layout (~93 MB; ws proven >= 113 MB in R2)
    __half* feat  = (__half*)d_ws;                          // 3*N*128 fp16
    short* Z      = (short*)(feat + (size_t)RR * Nn * 128); // 98304 bf16
    float* el     = (float*)(Z + 98304);                    // 3*N*4
    float* er     = el + (size_t)RR * Nn * 4;               // 3*N*4
    float* outbuf = er + (size_t)RR * Nn * 4;               // N*128 fp32
    float* wq     = outbuf + (size_t)Nn * 128;              // 4 * 3E floats
    int* counts    = (int*)(wq + (size_t)4 * RR * EE);      // 3*N
    int* row_start = counts + RR * Nn;                      // 3*N
    int* totals    = row_start + RR * Nn;                   // 4
    int* ord       = totals + 4;                            // 3*E
    int2* csr      = (int2*)(ord + RR * EE);                // 3*E int2 {src,dst}

    const int rowBlocks  = (Nn + 63) / 64;    // 782
    const int nodeBlocks = (Nn + 255) / 256;  // 196
    const int aggBlocks  = (Nn + 3) / 4;      // 12500
    const int edgeBlocks = (EE + 255) / 256;  // 1172
    const int edge4Blocks = (RR * EE / 4 + 255) / 256;  // 879

    // weight swizzle + CSR build
    wswz_kernel<<<48, 256, 0, stream>>>(W1, W2, Z);
    zero_kernel<<<(RR * Nn + 255) / 256, 256, 0, stream>>>(counts, totals);
    count_kernel<<<edge4Blocks, 256, 0, stream>>>(edges, counts, ord);
    alloc_kernel<<<dim3(nodeBlocks, RR), 256, 0, stream>>>(counts, row_start, totals);
    scatter_kernel<<<edge4Blocks, 256, 0, stream>>>(edges, ord, row_start, csr);

    // layer 1
    gemm_proj_mfma<false><<<rowBlocks, 256, 0, stream>>>(x, Z, feat);
    elr_kernel<<<(RR * Nn * 4 + 255) / 256, 256, 0, stream>>>((const __half2*)feat, al1, ar1, el, er);
    wexp_kernel<<<dim3(edgeBlocks, RR), 256, 0, stream>>>(csr, el, er, wq);
    agg_kernel<<<aggBlocks, 256, 0, stream>>>((const __half2*)feat, wq, csr, row_start, counts, b1, outbuf);

    // layer 2 (relu fused into A-stage)
    gemm_proj_mfma<true><<<rowBlocks, 256, 0, stream>>>(outbuf, Z + 49152, feat);
    elr_kernel<<<(RR * Nn * 4 + 255) / 256, 256, 0, stream>>>((const __half2*)feat, al2, ar2, el, er);
    wexp_kernel<<<dim3(edgeBlocks, RR), 256, 0, stream>>>(csr, el, er, wq);
    agg_kernel<<<aggBlocks, 256, 0, stream>>>((const __half2*)feat, wq, csr, row_start, counts, b2, outbuf);

    // final linear
    gemm_final_kernel<<<rowBlocks, 256, 0, stream>>>(outbuf, Wl, bl, out);
}

// Round 8
// 379.918 us; speedup vs baseline: 1.1547x; 1.0467x over previous
//
#include <hip/hip_runtime.h>
#include <hip/hip_bf16.h>
#include <hip/hip_fp16.h>

#define Nn 50000
#define RR 3
#define EE 300000

typedef __attribute__((ext_vector_type(8))) short short8;
typedef __attribute__((ext_vector_type(4))) short short4v;
typedef __attribute__((ext_vector_type(4))) float floatx4;

__device__ __forceinline__ short f2bf(float f) {
    __hip_bfloat16 h = __float2bfloat16(f);
    return *reinterpret_cast<short*>(&h);
}

// ---------------- init: zero counts/totals + W pre-swizzle (fused, independent work) ----------------
// blocks [0,586): zero; blocks [586, 634): wswz

__global__ void init_kernel(const float* __restrict__ W1, const float* __restrict__ W2,
                            short* __restrict__ Z, int* __restrict__ counts,
                            int* __restrict__ totals) {
    int bx = blockIdx.x;
    if (bx < 586) {
        int i = bx * 256 + threadIdx.x;
        if (i < RR * Nn) counts[i] = 0;
        if (i < 4) totals[i] = 0;
    } else {
        int idx = (bx - 586) * 256 + threadIdx.x;   // 2*3*4*8*64 = 12288
        if (idx >= 12288) return;
        int lane = idx & 63;
        int nt = (idx >> 6) & 7;
        int kt = (idx >> 9) & 3;
        int rl = idx >> 11;
        int layer = rl / 3, r = rl % 3;
        const float* W = (layer ? W2 : W1) + (size_t)r * 16384;
        int n = nt * 16 + (lane & 15);
        int k0 = kt * 32 + (lane >> 4) * 8;
        short8 v;
        #pragma unroll
        for (int j = 0; j < 8; ++j) v[j] = f2bf(W[(size_t)(k0 + j) * 128 + n]);
        *(short8*)&Z[(size_t)idx * 8] = v;
    }
}

// ---------------- CSR build ----------------

// 4 edges per thread (int4 loads); atomic returns the within-dst ordinal -> ord.
__global__ void count_kernel(const int* __restrict__ edges, int* __restrict__ counts,
                             int* __restrict__ ord) {
    int i = blockIdx.x * blockDim.x + threadIdx.x;   // RR*EE/4 threads
    if (i >= RR * EE / 4) return;
    int g = i * 4;
    int r = g / EE, e0 = g - r * EE;
    int4 d = *(const int4*)&edges[(size_t)r * 2 * EE + EE + e0];
    int* cb = counts + r * Nn;
    int4 o;
    o.x = atomicAdd(&cb[d.x], 1);
    o.y = atomicAdd(&cb[d.y], 1);
    o.z = atomicAdd(&cb[d.z], 1);
    o.w = atomicAdd(&cb[d.w], 1);
    *(int4*)&ord[g] = o;
}

__global__ __launch_bounds__(256) void alloc_kernel(const int* __restrict__ counts,
                                                    int* __restrict__ row_start,
                                                    int* __restrict__ totals) {
    __shared__ int s[256];
    __shared__ int base_s;
    int r = blockIdx.y;
    int tid = threadIdx.x;
    int n = blockIdx.x * 256 + tid;
    int idx = r * Nn + n;
    int c = (n < Nn) ? counts[idx] : 0;
    s[tid] = c;
    __syncthreads();
    #pragma unroll
    for (int off = 1; off < 256; off <<= 1) {
        int v = 0;
        if (tid >= off) v = s[tid - off];
        __syncthreads();
        if (tid >= off) s[tid] += v;
        __syncthreads();
    }
    if (tid == 255) base_s = atomicAdd(&totals[r], s[255]);
    __syncthreads();
    if (n < Nn) row_start[idx] = base_s + s[tid] - c;
}

// No atomics: slot = row_start[dst] + ord[edge]. src/dst stored as separate planes
// (agg reads only src -> 4 B/edge there).
__global__ void scatter_kernel(const int* __restrict__ edges, const int* __restrict__ ord,
                               const int* __restrict__ row_start,
                               int* __restrict__ csr_s, int* __restrict__ csr_d) {
    int i = blockIdx.x * blockDim.x + threadIdx.x;
    if (i >= RR * EE / 4) return;
    int g = i * 4;
    int r = g / EE, e0 = g - r * EE;
    int4 s4 = *(const int4*)&edges[(size_t)r * 2 * EE + e0];
    int4 d4 = *(const int4*)&edges[(size_t)r * 2 * EE + EE + e0];
    int4 o4 = *(const int4*)&ord[g];
    const int* rs = row_start + r * Nn;
    int* cs = csr_s + (size_t)r * EE;
    int* cd = csr_d + (size_t)r * EE;
    int p0 = rs[d4.x] + o4.x, p1 = rs[d4.y] + o4.y;
    int p2 = rs[d4.z] + o4.z, p3 = rs[d4.w] + o4.w;
    cs[p0] = s4.x; cs[p1] = s4.y; cs[p2] = s4.z; cs[p3] = s4.w;
    cd[p0] = d4.x; cd[p1] = d4.y; cd[p2] = d4.z; cd[p3] = d4.w;
}

// ---------------- MFMA GEMM: A[N,128] @ W[r][128,128] -> feat[r][N][128] fp16 ----------------
// LDS-staged epilogue: acc -> LDS (half) -> coalesced 16B stores.

template<bool RELU_A>
__global__ __launch_bounds__(256) void gemm_proj_mfma(const float* __restrict__ A,
                                                      const short* __restrict__ Z,
                                                      __half* __restrict__ C) {
    __shared__ short A_lds[64 * 136];   // reused as __half[64*136] for the epilogue
    int tid = threadIdx.x;
    int row0 = blockIdx.x * 64;
    #pragma unroll
    for (int p = 0; p < 8; ++p) {
        int f = p * 256 + tid;
        int row = f >> 5;
        int c4 = (f & 31) * 4;
        float4 v = make_float4(0.f, 0.f, 0.f, 0.f);
        if (row0 + row < Nn) v = *(const float4*)&A[(size_t)(row0 + row) * 128 + c4];
        if (RELU_A) {
            v.x = fmaxf(v.x, 0.f); v.y = fmaxf(v.y, 0.f);
            v.z = fmaxf(v.z, 0.f); v.w = fmaxf(v.w, 0.f);
        }
        short4v sv;
        sv[0] = f2bf(v.x); sv[1] = f2bf(v.y); sv[2] = f2bf(v.z); sv[3] = f2bf(v.w);
        *(short4v*)&A_lds[row * 136 + c4] = sv;
    }
    __syncthreads();
    int wave = tid >> 6, lane = tid & 63;
    int m = lane & 15, q = lane >> 4;
    short8 af[4];
    #pragma unroll
    for (int kt = 0; kt < 4; ++kt)
        af[kt] = *(short8*)&A_lds[(wave * 16 + m) * 136 + kt * 32 + q * 8];
    __syncthreads();   // A_lds dead; reuse as epilogue buffer below
    __half* lds_h = (__half*)A_lds;
    for (int r = 0; r < RR; ++r) {
        floatx4 acc[8];
        #pragma unroll
        for (int nt = 0; nt < 8; ++nt) acc[nt] = (floatx4)(0.f);
        const short* Zr = Z + (size_t)r * 16384;
        #pragma unroll
        for (int kt = 0; kt < 4; ++kt) {
            #pragma unroll
            for (int nt = 0; nt < 8; ++nt) {
                short8 bf = *(const short8*)&Zr[(size_t)(kt * 8 + nt) * 512 + lane * 8];
                acc[nt] = __builtin_amdgcn_mfma_f32_16x16x32_bf16(af[kt], bf, acc[nt], 0, 0, 0);
            }
        }
        // stage C tile to LDS
        #pragma unroll
        for (int nt = 0; nt < 8; ++nt) {
            int col = nt * 16 + m;
            #pragma unroll
            for (int reg = 0; reg < 4; ++reg)
                lds_h[(wave * 16 + q * 4 + reg) * 136 + col] = __float2half(acc[nt][reg]);
        }
        __syncthreads();
        // coalesced 16B stores: 1024 chunks of 8 halfs, 4 per thread
        __half* Cr = C + (size_t)r * Nn * 128;
        #pragma unroll
        for (int p = 0; p < 4; ++p) {
            int lin = p * 256 + tid;
            int row = lin >> 4, c8 = (lin & 15) * 8;
            if (row0 + row < Nn)
                *(short8*)&Cr[(size_t)(row0 + row) * 128 + c8] = *(short8*)&lds_h[row * 136 + c8];
        }
        __syncthreads();   // before next relation overwrites lds_h
    }
}

// ---------------- Final GEMM: A[N,128] @ Wl[128,64] + bl -> out [N,64] fp32 ----------------

__global__ __launch_bounds__(256) void gemm_final_kernel(const float* __restrict__ A,
                                                         const float* __restrict__ Wl,
                                                         const float* __restrict__ bl,
                                                         float* __restrict__ out) {
    __shared__ float As[16][65];
    __shared__ float Bs[16][65];
    int tid = threadIdx.x;
    int row0 = blockIdx.x * 64;
    float acc[4][4] = {};
    int tx = tid & 15, ty = tid >> 4;
    for (int k0 = 0; k0 < 128; k0 += 16) {
        {
            int mm = tid >> 2, c = (tid & 3) * 4;
            int row = row0 + mm;
            float4 v = make_float4(0.f, 0.f, 0.f, 0.f);
            if (row < Nn) v = *(const float4*)&A[(size_t)row * 128 + k0 + c];
            As[c + 0][mm] = v.x; As[c + 1][mm] = v.y; As[c + 2][mm] = v.z; As[c + 3][mm] = v.w;
        }
        {
            int kk = tid >> 4, j = (tid & 15) * 4;
            float4 v = *(const float4*)&Wl[(size_t)(k0 + kk) * 64 + j];
            *(float4*)&Bs[kk][j] = v;
        }
        __syncthreads();
        #pragma unroll
        for (int kk = 0; kk < 16; ++kk) {
            float4 a = *(const float4*)&As[kk][ty * 4];
            float4 b = *(const float4*)&Bs[kk][tx * 4];
            float av[4] = {a.x, a.y, a.z, a.w};
            float bv[4] = {b.x, b.y, b.z, b.w};
            #pragma unroll
            for (int i = 0; i < 4; ++i)
                #pragma unroll
                for (int j = 0; j < 4; ++j) acc[i][j] += av[i] * bv[j];
        }
        __syncthreads();
    }
    float4 bias = *(const float4*)&bl[tx * 4];
    #pragma unroll
    for (int i = 0; i < 4; ++i) {
        int row = row0 + ty * 4 + i;
        if (row >= Nn) continue;
        float4 v = make_float4(acc[i][0] + bias.x, acc[i][1] + bias.y,
                               acc[i][2] + bias.z, acc[i][3] + bias.w);
        *(float4*)&out[(size_t)row * 64 + tx * 4] = v;
    }
}

// ---------------- el/er from fp16 feat ----------------

__global__ void elr_kernel(const __half2* __restrict__ feat2, const float* __restrict__ al,
                           const float* __restrict__ ar, float* __restrict__ el,
                           float* __restrict__ er) {
    int i = blockIdx.x * blockDim.x + threadIdx.x;
    if (i >= RR * Nn * 4) return;
    int h = i & 3;
    int nr = i >> 2;
    int n = nr % Nn;
    int r = nr / Nn;
    const __half2* f = feat2 + ((size_t)(r * Nn + n) * 64 + h * 16);
    const float* alp = al + r * 128 + h * 32;
    const float* arp = ar + r * 128 + h * 32;
    float sl = 0.f, sr = 0.f;
    #pragma unroll
    for (int d = 0; d < 16; ++d) {
        float2 v = __half22float2(f[d]);
        sl += v.x * alp[2 * d] + v.y * alp[2 * d + 1];
        sr += v.x * arp[2 * d] + v.y * arp[2 * d + 1];
    }
    el[i] = sl;
    er[i] = sr;
}

// ---------------- edge-parallel softmax weights ----------------

__global__ __launch_bounds__(256) void wexp_kernel(const int* __restrict__ csr_s,
                                                   const int* __restrict__ csr_d,
                                                   const float* __restrict__ el,
                                                   const float* __restrict__ er,
                                                   float* __restrict__ wq) {
    int r = blockIdx.y;
    int k = blockIdx.x * 256 + threadIdx.x;
    if (k >= EE) return;
    size_t gk = (size_t)r * EE + k;
    int es = csr_s[gk], ed = csr_d[gk];
    float4 l4 = *(const float4*)&el[(size_t)(r * Nn + es) * 4];
    float4 r4 = *(const float4*)&er[(size_t)(r * Nn + ed) * 4];
    float lv[4] = {l4.x, l4.y, l4.z, l4.w};
    float rv[4] = {r4.x, r4.y, r4.z, r4.w};
    #pragma unroll
    for (int h = 0; h < 4; ++h) {
        float x = lv[h] + rv[h];
        x = (x > 0.f) ? x : 0.2f * x;
        wq[(size_t)h * (RR * EE) + gk] = __expf(x);
    }
}

// ---------------- aggregation: one wave per dst node; all relation setup loads hoisted ----------------
// exp(e)/sum(exp(e)) == softmax (no-max form); |e| <~ 1.5 here so no overflow risk.
// Mean degree = 6 -> first chunk (<=16 edges) covers almost all nodes; preload all 3
// relations' first chunks upfront for memory-level parallelism.

__global__ __launch_bounds__(256) void agg_kernel(const __half2* __restrict__ feat2,
                                                  const float* __restrict__ wq,
                                                  const int* __restrict__ csr_s,
                                                  const int* __restrict__ row_start,
                                                  const int* __restrict__ counts,
                                                  const float* __restrict__ b,
                                                  float* __restrict__ out) {
    int wave = threadIdx.x >> 6;
    int lane = threadIdx.x & 63;
    int n = blockIdx.x * 4 + wave;
    if (n >= Nn) return;
    int h = lane >> 4;
    int hl = lane & 15;
    int grp = lane & 48;
    int t2 = lane * 2;
    int cntA[RR], stA[RR], sC[RR];
    float wC[RR];
    #pragma unroll
    for (int r = 0; r < RR; ++r) {
        cntA[r] = counts[r * Nn + n];
        stA[r] = row_start[r * Nn + n];
    }
    #pragma unroll
    for (int r = 0; r < RR; ++r) {
        sC[r] = 0; wC[r] = 0.f;
        if (hl < cntA[r]) {
            int idx = stA[r] + hl;
            sC[r] = csr_s[(size_t)r * EE + idx];
            wC[r] = wq[(size_t)h * (RR * EE) + (size_t)r * EE + idx];
        }
    }
    float accx = b[t2] + b[128 + t2] + b[256 + t2];
    float accy = b[t2 + 1] + b[128 + t2 + 1] + b[256 + t2 + 1];
    #pragma unroll
    for (int r = 0; r < RR; ++r) {
        int cnt = cntA[r];
        if (cnt == 0) continue;
        const __half2* fr = feat2 + (size_t)r * Nn * 64;
        float den = 0.f, numx = 0.f, numy = 0.f;
        int s_l = sC[r];
        float w_l = wC[r];
        int i0 = 0;
        while (true) {
            int mm = cnt - i0; if (mm > 16) mm = 16;
            int j = 0;
            for (; j + 3 < mm; j += 4) {
                int s0 = __shfl(s_l, j);
                int s1 = __shfl(s_l, j + 1);
                int s2 = __shfl(s_l, j + 2);
                int s3 = __shfl(s_l, j + 3);
                float w0 = __shfl(w_l, grp | j);
                float w1 = __shfl(w_l, grp | (j + 1));
                float w2 = __shfl(w_l, grp | (j + 2));
                float w3 = __shfl(w_l, grp | (j + 3));
                __half2 f0 = fr[(size_t)s0 * 64 + lane];
                __half2 f1 = fr[(size_t)s1 * 64 + lane];
                __half2 f2 = fr[(size_t)s2 * 64 + lane];
                __half2 f3 = fr[(size_t)s3 * 64 + lane];
                float2 g0 = __half22float2(f0), g1 = __half22float2(f1);
                float2 g2 = __half22float2(f2), g3 = __half22float2(f3);
                den += (w0 + w1) + (w2 + w3);
                numx += w0 * g0.x + w1 * g1.x + w2 * g2.x + w3 * g3.x;
                numy += w0 * g0.y + w1 * g1.y + w2 * g2.y + w3 * g3.y;
            }
            for (; j < mm; ++j) {
                int s0 = __shfl(s_l, j);
                float w0 = __shfl(w_l, grp | j);
                __half2 f0 = fr[(size_t)s0 * 64 + lane];
                float2 g0 = __half22float2(f0);
                den += w0; numx += w0 * g0.x; numy += w0 * g0.y;
            }
            i0 += 16;
            if (i0 >= cnt) break;
            // rare tail chunks (P(cnt>16) ~ 0.2% at Poisson(6))
            s_l = 0; w_l = 0.f;
            if (i0 + hl < cnt) {
                int idx = stA[r] + i0 + hl;
                s_l = csr_s[(size_t)r * EE + idx];
                w_l = wq[(size_t)h * (RR * EE) + (size_t)r * EE + idx];
            }
        }
        float inv = 1.f / den;
        accx += numx * inv;
        accy += numy * inv;
    }
    *(float2*)&out[(size_t)n * 128 + t2] = make_float2(accx, accy);
}

// ---------------- launch ----------------

extern "C" void kernel_launch(void* const* d_in, const int* in_sizes, int n_in,
                              void* d_out, int out_size, void* d_ws, size_t ws_size,
                              hipStream_t stream) {
    const float* x   = (const float*)d_in[0];
    const int*  edges = (const int*)d_in[1];
    const float* W1  = (const float*)d_in[2];
    const float* al1 = (const float*)d_in[3];
    const float* ar1 = (const float*)d_in[4];
    const float* b1  = (const float*)d_in[5];
    const float* W2  = (const float*)d_in[6];
    const float* al2 = (const float*)d_in[7];
    const float* ar2 = (const float*)d_in[8];
    const float* b2  = (const float*)d_in[9];
    const float* Wl  = (const float*)d_in[10];
    const float* bl  = (const float*)d_in[11];
    float* out = (float*)d_out;

    // workspace layout (~95 MB; ws proven >= 113 MB in R2)
    __half* feat  = (__half*)d_ws;                          // 3*N*128 fp16
    short* Z      = (short*)(feat + (size_t)RR * Nn * 128); // 98304 bf16
    float* el     = (float*)(Z + 98304);                    // 3*N*4
    float* er     = el + (size_t)RR * Nn * 4;               // 3*N*4
    float* outbuf = er + (size_t)RR * Nn * 4;               // N*128 fp32
    float* wq     = outbuf + (size_t)Nn * 128;              // 4 * 3E floats
    int* counts    = (int*)(wq + (size_t)4 * RR * EE);      // 3*N
    int* row_start = counts + RR * Nn;                      // 3*N
    int* totals    = row_start + RR * Nn;                   // 4
    int* ord       = totals + 4;                            // 3*E
    int* csr_s     = ord + RR * EE;                         // 3*E
    int* csr_d     = csr_s + RR * EE;                       // 3*E

    const int rowBlocks  = (Nn + 63) / 64;    // 782
    const int nodeBlocks = (Nn + 255) / 256;  // 196
    const int aggBlocks  = (Nn + 3) / 4;      // 12500
    const int edgeBlocks = (EE + 255) / 256;  // 1172
    const int edge4Blocks = (RR * EE / 4 + 255) / 256;  // 879

    // init (zero + wswz) + CSR build
    init_kernel<<<634, 256, 0, stream>>>(W1, W2, Z, counts, totals);
    count_kernel<<<edge4Blocks, 256, 0, stream>>>(edges, counts, ord);
    alloc_kernel<<<dim3(nodeBlocks, RR), 256, 0, stream>>>(counts, row_start, totals);
    scatter_kernel<<<edge4Blocks, 256, 0, stream>>>(edges, ord, row_start, csr_s, csr_d);

    // layer 1
    gemm_proj_mfma<false><<<rowBlocks, 256, 0, stream>>>(x, Z, feat);
    elr_kernel<<<(RR * Nn * 4 + 255) / 256, 256, 0, stream>>>((const __half2*)feat, al1, ar1, el, er);
    wexp_kernel<<<dim3(edgeBlocks, RR), 256, 0, stream>>>(csr_s, csr_d, el, er, wq);
    agg_kernel<<<aggBlocks, 256, 0, stream>>>((const __half2*)feat, wq, csr_s, row_start, counts, b1, outbuf);

    // layer 2 (relu fused into A-stage)
    gemm_proj_mfma<true><<<rowBlocks, 256, 0, stream>>>(outbuf, Z + 49152, feat);
    elr_kernel<<<(RR * Nn * 4 + 255) / 256, 256, 0, stream>>>((const __half2*)feat, al2, ar2, el, er);
    wexp_kernel<<<dim3(edgeBlocks, RR), 256, 0, stream>>>(csr_s, csr_d, el, er, wq);
    agg_kernel<<<aggBlocks, 256, 0, stream>>>((const __half2*)feat, wq, csr_s, row_start, counts, b2, outbuf);

    // final linear
    gemm_final_kernel<<<rowBlocks, 256, 0, stream>>>(outbuf, Wl, bl, out);
}

// Round 9
// 343.921 us; speedup vs baseline: 1.2756x; 1.1047x over previous
//
#include <hip/hip_runtime.h>
#include <hip/hip_bf16.h>
#include <hip/hip_fp16.h>

#define Nn 50000
#define RR 3
#define EE 300000

typedef __attribute__((ext_vector_type(8))) short short8;
typedef __attribute__((ext_vector_type(4))) short short4v;
typedef __attribute__((ext_vector_type(4))) float floatx4;

__device__ __forceinline__ short f2bf(float f) {
    __hip_bfloat16 h = __float2bfloat16(f);
    return *reinterpret_cast<short*>(&h);
}

// ---------------- init: zero counts/totals + W pre-swizzle ----------------

__global__ void init_kernel(const float* __restrict__ W1, const float* __restrict__ W2,
                            short* __restrict__ Z, int* __restrict__ counts,
                            int* __restrict__ totals) {
    int bx = blockIdx.x;
    if (bx < 586) {
        int i = bx * 256 + threadIdx.x;
        if (i < RR * Nn) counts[i] = 0;
        if (i < 4) totals[i] = 0;
    } else {
        int idx = (bx - 586) * 256 + threadIdx.x;   // 2*3*4*8*64 = 12288
        if (idx >= 12288) return;
        int lane = idx & 63;
        int nt = (idx >> 6) & 7;
        int kt = (idx >> 9) & 3;
        int rl = idx >> 11;
        int layer = rl / 3, r = rl % 3;
        const float* W = (layer ? W2 : W1) + (size_t)r * 16384;
        int n = nt * 16 + (lane & 15);
        int k0 = kt * 32 + (lane >> 4) * 8;
        short8 v;
        #pragma unroll
        for (int j = 0; j < 8; ++j) v[j] = f2bf(W[(size_t)(k0 + j) * 128 + n]);
        *(short8*)&Z[(size_t)idx * 8] = v;
    }
}

// ---------------- CSR build ----------------

// 8 edges per thread; atomic returns the within-dst ordinal -> ord.
__global__ void count_kernel(const int* __restrict__ edges, int* __restrict__ counts,
                             int* __restrict__ ord) {
    int i = blockIdx.x * blockDim.x + threadIdx.x;   // RR*EE/8 threads
    if (i >= RR * EE / 8) return;
    int g = i * 8;
    int r = g / EE, e0 = g - r * EE;
    const int* db = &edges[(size_t)r * 2 * EE + EE + e0];
    int4 d0 = *(const int4*)db;
    int4 d1 = *(const int4*)(db + 4);
    int* cb = counts + r * Nn;
    int4 o0, o1;
    o0.x = atomicAdd(&cb[d0.x], 1);
    o0.y = atomicAdd(&cb[d0.y], 1);
    o0.z = atomicAdd(&cb[d0.z], 1);
    o0.w = atomicAdd(&cb[d0.w], 1);
    o1.x = atomicAdd(&cb[d1.x], 1);
    o1.y = atomicAdd(&cb[d1.y], 1);
    o1.z = atomicAdd(&cb[d1.z], 1);
    o1.w = atomicAdd(&cb[d1.w], 1);
    *(int4*)&ord[g] = o0;
    *(int4*)&ord[g + 4] = o1;
}

__global__ __launch_bounds__(256) void alloc_kernel(const int* __restrict__ counts,
                                                    int* __restrict__ row_start,
                                                    int* __restrict__ totals) {
    __shared__ int s[256];
    __shared__ int base_s;
    int r = blockIdx.y;
    int tid = threadIdx.x;
    int n = blockIdx.x * 256 + tid;
    int idx = r * Nn + n;
    int c = (n < Nn) ? counts[idx] : 0;
    s[tid] = c;
    __syncthreads();
    #pragma unroll
    for (int off = 1; off < 256; off <<= 1) {
        int v = 0;
        if (tid >= off) v = s[tid - off];
        __syncthreads();
        if (tid >= off) s[tid] += v;
        __syncthreads();
    }
    if (tid == 255) base_s = atomicAdd(&totals[r], s[255]);
    __syncthreads();
    if (n < Nn) row_start[idx] = base_s + s[tid] - c;
}

// No atomics: slot = row_start[dst] + ord[edge]; 8 edges/thread.
__global__ void scatter_kernel(const int* __restrict__ edges, const int* __restrict__ ord,
                               const int* __restrict__ row_start,
                               int* __restrict__ csr_s, int* __restrict__ csr_d) {
    int i = blockIdx.x * blockDim.x + threadIdx.x;
    if (i >= RR * EE / 8) return;
    int g = i * 8;
    int r = g / EE, e0 = g - r * EE;
    const int* sb = &edges[(size_t)r * 2 * EE + e0];
    const int* db = sb + EE;
    int4 s0 = *(const int4*)sb, s1 = *(const int4*)(sb + 4);
    int4 d0 = *(const int4*)db, d1 = *(const int4*)(db + 4);
    int4 o0 = *(const int4*)&ord[g], o1 = *(const int4*)&ord[g + 4];
    const int* rs = row_start + r * Nn;
    int* cs = csr_s + (size_t)r * EE;
    int* cd = csr_d + (size_t)r * EE;
    int p0 = rs[d0.x] + o0.x, p1 = rs[d0.y] + o0.y;
    int p2 = rs[d0.z] + o0.z, p3 = rs[d0.w] + o0.w;
    int p4 = rs[d1.x] + o1.x, p5 = rs[d1.y] + o1.y;
    int p6 = rs[d1.z] + o1.z, p7 = rs[d1.w] + o1.w;
    cs[p0] = s0.x; cs[p1] = s0.y; cs[p2] = s0.z; cs[p3] = s0.w;
    cs[p4] = s1.x; cs[p5] = s1.y; cs[p6] = s1.z; cs[p7] = s1.w;
    cd[p0] = d0.x; cd[p1] = d0.y; cd[p2] = d0.z; cd[p3] = d0.w;
    cd[p4] = d1.x; cd[p5] = d1.y; cd[p6] = d1.z; cd[p7] = d1.w;
}

// ---------------- MFMA GEMM + fused el/er epilogue ----------------
// A[N,128] @ W[r][128,128] -> feat[r][N][128] fp16, plus el/er[r][n][h] from the
// LDS-staged C tile (saves the separate elr kernel's 38 MB feat re-read).

template<bool RELU_A>
__global__ __launch_bounds__(256) void gemm_proj_mfma(const float* __restrict__ A,
                                                      const short* __restrict__ Z,
                                                      const float* __restrict__ al,
                                                      const float* __restrict__ ar,
                                                      __half* __restrict__ C,
                                                      float* __restrict__ el,
                                                      float* __restrict__ er) {
    __shared__ short A_lds[64 * 136];   // reused as __half[64*136] for the epilogue
    __shared__ float al_lds[384], ar_lds[384];
    int tid = threadIdx.x;
    int row0 = blockIdx.x * 64;
    // stage al/ar (R*H*D = 384 floats each)
    if (tid < 128) { al_lds[256 + tid] = al[256 + tid]; ar_lds[256 + tid] = ar[256 + tid]; }
    al_lds[tid] = al[tid]; ar_lds[tid] = ar[tid];
    #pragma unroll
    for (int p = 0; p < 8; ++p) {
        int f = p * 256 + tid;
        int row = f >> 5;
        int c4 = (f & 31) * 4;
        float4 v = make_float4(0.f, 0.f, 0.f, 0.f);
        if (row0 + row < Nn) v = *(const float4*)&A[(size_t)(row0 + row) * 128 + c4];
        if (RELU_A) {
            v.x = fmaxf(v.x, 0.f); v.y = fmaxf(v.y, 0.f);
            v.z = fmaxf(v.z, 0.f); v.w = fmaxf(v.w, 0.f);
        }
        short4v sv;
        sv[0] = f2bf(v.x); sv[1] = f2bf(v.y); sv[2] = f2bf(v.z); sv[3] = f2bf(v.w);
        *(short4v*)&A_lds[row * 136 + c4] = sv;
    }
    __syncthreads();
    int wave = tid >> 6, lane = tid & 63;
    int m = lane & 15, q = lane >> 4;
    short8 af[4];
    #pragma unroll
    for (int kt = 0; kt < 4; ++kt)
        af[kt] = *(short8*)&A_lds[(wave * 16 + m) * 136 + kt * 32 + q * 8];
    __syncthreads();   // A_lds dead; reuse as epilogue buffer
    __half* lds_h = (__half*)A_lds;
    int row8 = tid >> 2;      // epilogue mapping: 64 rows x 4 heads
    int hh = tid & 3;
    for (int r = 0; r < RR; ++r) {
        floatx4 acc[8];
        #pragma unroll
        for (int nt = 0; nt < 8; ++nt) acc[nt] = (floatx4)(0.f);
        const short* Zr = Z + (size_t)r * 16384;
        #pragma unroll
        for (int kt = 0; kt < 4; ++kt) {
            #pragma unroll
            for (int nt = 0; nt < 8; ++nt) {
                short8 bf = *(const short8*)&Zr[(size_t)(kt * 8 + nt) * 512 + lane * 8];
                acc[nt] = __builtin_amdgcn_mfma_f32_16x16x32_bf16(af[kt], bf, acc[nt], 0, 0, 0);
            }
        }
        // stage C tile to LDS (fp16)
        #pragma unroll
        for (int nt = 0; nt < 8; ++nt) {
            int col = nt * 16 + m;
            #pragma unroll
            for (int reg = 0; reg < 4; ++reg)
                lds_h[(wave * 16 + q * 4 + reg) * 136 + col] = __float2half(acc[nt][reg]);
        }
        __syncthreads();
        // coalesced 16B stores
        __half* Cr = C + (size_t)r * Nn * 128;
        #pragma unroll
        for (int p = 0; p < 4; ++p) {
            int lin = p * 256 + tid;
            int row = lin >> 4, c8 = (lin & 15) * 8;
            if (row0 + row < Nn)
                *(short8*)&Cr[(size_t)(row0 + row) * 128 + c8] = *(short8*)&lds_h[row * 136 + c8];
        }
        // fused el/er: one (row, head) per thread, dot over 32 cols from LDS
        {
            const __half2* fp = (const __half2*)&lds_h[row8 * 136 + hh * 32];
            const float* alp = &al_lds[r * 128 + hh * 32];
            const float* arp = &ar_lds[r * 128 + hh * 32];
            float sl = 0.f, sr = 0.f;
            #pragma unroll
            for (int d = 0; d < 16; ++d) {
                float2 v = __half22float2(fp[d]);
                sl += v.x * alp[2 * d] + v.y * alp[2 * d + 1];
                sr += v.x * arp[2 * d] + v.y * arp[2 * d + 1];
            }
            if (row0 + row8 < Nn) {
                size_t ei = (size_t)(r * Nn + row0 + row8) * 4 + hh;
                el[ei] = sl;
                er[ei] = sr;
            }
        }
        __syncthreads();   // before next relation overwrites lds_h
    }
}

// ---------------- Final GEMM: A[N,128] @ Wl[128,64] + bl -> out [N,64] fp32 ----------------

__global__ __launch_bounds__(256) void gemm_final_kernel(const float* __restrict__ A,
                                                         const float* __restrict__ Wl,
                                                         const float* __restrict__ bl,
                                                         float* __restrict__ out) {
    __shared__ float As[16][65];
    __shared__ float Bs[16][65];
    int tid = threadIdx.x;
    int row0 = blockIdx.x * 64;
    float acc[4][4] = {};
    int tx = tid & 15, ty = tid >> 4;
    for (int k0 = 0; k0 < 128; k0 += 16) {
        {
            int mm = tid >> 2, c = (tid & 3) * 4;
            int row = row0 + mm;
            float4 v = make_float4(0.f, 0.f, 0.f, 0.f);
            if (row < Nn) v = *(const float4*)&A[(size_t)row * 128 + k0 + c];
            As[c + 0][mm] = v.x; As[c + 1][mm] = v.y; As[c + 2][mm] = v.z; As[c + 3][mm] = v.w;
        }
        {
            int kk = tid >> 4, j = (tid & 15) * 4;
            float4 v = *(const float4*)&Wl[(size_t)(k0 + kk) * 64 + j];
            *(float4*)&Bs[kk][j] = v;
        }
        __syncthreads();
        #pragma unroll
        for (int kk = 0; kk < 16; ++kk) {
            float4 a = *(const float4*)&As[kk][ty * 4];
            float4 b = *(const float4*)&Bs[kk][tx * 4];
            float av[4] = {a.x, a.y, a.z, a.w};
            float bv[4] = {b.x, b.y, b.z, b.w};
            #pragma unroll
            for (int i = 0; i < 4; ++i)
                #pragma unroll
                for (int j = 0; j < 4; ++j) acc[i][j] += av[i] * bv[j];
        }
        __syncthreads();
    }
    float4 bias = *(const float4*)&bl[tx * 4];
    #pragma unroll
    for (int i = 0; i < 4; ++i) {
        int row = row0 + ty * 4 + i;
        if (row >= Nn) continue;
        float4 v = make_float4(acc[i][0] + bias.x, acc[i][1] + bias.y,
                               acc[i][2] + bias.z, acc[i][3] + bias.w);
        *(float4*)&out[(size_t)row * 64 + tx * 4] = v;
    }
}

// ---------------- edge-parallel softmax weights ----------------

__global__ __launch_bounds__(256) void wexp_kernel(const int* __restrict__ csr_s,
                                                   const int* __restrict__ csr_d,
                                                   const float* __restrict__ el,
                                                   const float* __restrict__ er,
                                                   float* __restrict__ wq) {
    int r = blockIdx.y;
    int k = blockIdx.x * 256 + threadIdx.x;
    if (k >= EE) return;
    size_t gk = (size_t)r * EE + k;
    int es = csr_s[gk], ed = csr_d[gk];
    float4 l4 = *(const float4*)&el[(size_t)(r * Nn + es) * 4];
    float4 r4 = *(const float4*)&er[(size_t)(r * Nn + ed) * 4];
    float lv[4] = {l4.x, l4.y, l4.z, l4.w};
    float rv[4] = {r4.x, r4.y, r4.z, r4.w};
    #pragma unroll
    for (int h = 0; h < 4; ++h) {
        float x = lv[h] + rv[h];
        x = (x > 0.f) ? x : 0.2f * x;
        wq[(size_t)h * (RR * EE) + gk] = __expf(x);
    }
}

// ---------------- aggregation: one wave per dst node; predicated 4-edge groups ----------------
// exp(e)/sum(exp(e)) == softmax (no-max form); |e| <~ 1.5 here so no overflow risk.
// Invalid lanes carry s=0,w=0 -> dummy edges contribute nothing (feat row 0 cache-hot).

__global__ __launch_bounds__(256) void agg_kernel(const __half2* __restrict__ feat2,
                                                  const float* __restrict__ wq,
                                                  const int* __restrict__ csr_s,
                                                  const int* __restrict__ row_start,
                                                  const int* __restrict__ counts,
                                                  const float* __restrict__ b,
                                                  float* __restrict__ out) {
    int wave = threadIdx.x >> 6;
    int lane = threadIdx.x & 63;
    int n = blockIdx.x * 4 + wave;
    if (n >= Nn) return;
    int h = lane >> 4;
    int hl = lane & 15;
    int grp = lane & 48;
    int t2 = lane * 2;
    int cntA[RR], stA[RR], sC[RR];
    float wC[RR];
    #pragma unroll
    for (int r = 0; r < RR; ++r) {
        cntA[r] = counts[r * Nn + n];
        stA[r] = row_start[r * Nn + n];
    }
    #pragma unroll
    for (int r = 0; r < RR; ++r) {
        sC[r] = 0; wC[r] = 0.f;
        if (hl < cntA[r]) {
            int idx = stA[r] + hl;
            sC[r] = csr_s[(size_t)r * EE + idx];
            wC[r] = wq[(size_t)h * (RR * EE) + (size_t)r * EE + idx];
        }
    }
    float accx = b[t2] + b[128 + t2] + b[256 + t2];
    float accy = b[t2 + 1] + b[128 + t2 + 1] + b[256 + t2 + 1];
    #pragma unroll
    for (int r = 0; r < RR; ++r) {
        int cnt = cntA[r];
        if (cnt == 0) continue;
        const __half2* fr = feat2 + (size_t)r * Nn * 64;
        float den = 0.f, numx = 0.f, numy = 0.f;
        int s_l = sC[r];
        float w_l = wC[r];
        int i0 = 0;
        while (true) {
            int mm = cnt - i0; if (mm > 16) mm = 16;
            int mm4 = (mm + 3) & ~3;
            for (int j = 0; j < mm4; j += 4) {
                int s0 = __shfl(s_l, j);
                int s1 = __shfl(s_l, j + 1);
                int s2 = __shfl(s_l, j + 2);
                int s3 = __shfl(s_l, j + 3);
                float w0 = __shfl(w_l, grp | j);
                float w1 = __shfl(w_l, grp | (j + 1));
                float w2 = __shfl(w_l, grp | (j + 2));
                float w3 = __shfl(w_l, grp | (j + 3));
                __half2 f0 = fr[(size_t)s0 * 64 + lane];
                __half2 f1 = fr[(size_t)s1 * 64 + lane];
                __half2 f2 = fr[(size_t)s2 * 64 + lane];
                __half2 f3 = fr[(size_t)s3 * 64 + lane];
                float2 g0 = __half22float2(f0), g1 = __half22float2(f1);
                float2 g2 = __half22float2(f2), g3 = __half22float2(f3);
                den += (w0 + w1) + (w2 + w3);
                numx += w0 * g0.x + w1 * g1.x + w2 * g2.x + w3 * g3.x;
                numy += w0 * g0.y + w1 * g1.y + w2 * g2.y + w3 * g3.y;
            }
            i0 += 16;
            if (i0 >= cnt) break;
            // rare tail chunks (P(cnt>16) ~ 0.2% at mean degree 6)
            s_l = 0; w_l = 0.f;
            if (i0 + hl < cnt) {
                int idx = stA[r] + i0 + hl;
                s_l = csr_s[(size_t)r * EE + idx];
                w_l = wq[(size_t)h * (RR * EE) + (size_t)r * EE + idx];
            }
        }
        float inv = 1.f / den;
        accx += numx * inv;
        accy += numy * inv;
    }
    *(float2*)&out[(size_t)n * 128 + t2] = make_float2(accx, accy);
}

// ---------------- launch ----------------

extern "C" void kernel_launch(void* const* d_in, const int* in_sizes, int n_in,
                              void* d_out, int out_size, void* d_ws, size_t ws_size,
                              hipStream_t stream) {
    const float* x   = (const float*)d_in[0];
    const int*  edges = (const int*)d_in[1];
    const float* W1  = (const float*)d_in[2];
    const float* al1 = (const float*)d_in[3];
    const float* ar1 = (const float*)d_in[4];
    const float* b1  = (const float*)d_in[5];
    const float* W2  = (const float*)d_in[6];
    const float* al2 = (const float*)d_in[7];
    const float* ar2 = (const float*)d_in[8];
    const float* b2  = (const float*)d_in[9];
    const float* Wl  = (const float*)d_in[10];
    const float* bl  = (const float*)d_in[11];
    float* out = (float*)d_out;

    // workspace layout (~95 MB; ws proven >= 113 MB in R2)
    __half* feat  = (__half*)d_ws;                          // 3*N*128 fp16
    short* Z      = (short*)(feat + (size_t)RR * Nn * 128); // 98304 bf16
    float* el     = (float*)(Z + 98304);                    // 3*N*4
    float* er     = el + (size_t)RR * Nn * 4;               // 3*N*4
    float* outbuf = er + (size_t)RR * Nn * 4;               // N*128 fp32
    float* wq     = outbuf + (size_t)Nn * 128;              // 4 * 3E floats
    int* counts    = (int*)(wq + (size_t)4 * RR * EE);      // 3*N
    int* row_start = counts + RR * Nn;                      // 3*N
    int* totals    = row_start + RR * Nn;                   // 4
    int* ord       = totals + 4;                            // 3*E
    int* csr_s     = ord + RR * EE;                         // 3*E
    int* csr_d     = csr_s + RR * EE;                       // 3*E

    const int rowBlocks  = (Nn + 63) / 64;    // 782
    const int nodeBlocks = (Nn + 255) / 256;  // 196
    const int aggBlocks  = (Nn + 3) / 4;      // 12500
    const int edgeBlocks = (EE + 255) / 256;  // 1172
    const int edge8Blocks = (RR * EE / 8 + 255) / 256;  // 440

    // init (zero + wswz) + CSR build
    init_kernel<<<634, 256, 0, stream>>>(W1, W2, Z, counts, totals);
    count_kernel<<<edge8Blocks, 256, 0, stream>>>(edges, counts, ord);
    alloc_kernel<<<dim3(nodeBlocks, RR), 256, 0, stream>>>(counts, row_start, totals);
    scatter_kernel<<<edge8Blocks, 256, 0, stream>>>(edges, ord, row_start, csr_s, csr_d);

    // layer 1 (el/er fused into gemm epilogue)
    gemm_proj_mfma<false><<<rowBlocks, 256, 0, stream>>>(x, Z, al1, ar1, feat, el, er);
    wexp_kernel<<<dim3(edgeBlocks, RR), 256, 0, stream>>>(csr_s, csr_d, el, er, wq);
    agg_kernel<<<aggBlocks, 256, 0, stream>>>((const __half2*)feat, wq, csr_s, row_start, counts, b1, outbuf);

    // layer 2 (relu fused into A-stage)
    gemm_proj_mfma<true><<<rowBlocks, 256, 0, stream>>>(outbuf, Z + 49152, al2, ar2, feat, el, er);
    wexp_kernel<<<dim3(edgeBlocks, RR), 256, 0, stream>>>(csr_s, csr_d, el, er, wq);
    agg_kernel<<<aggBlocks, 256, 0, stream>>>((const __half2*)feat, wq, csr_s, row_start, counts, b2, outbuf);

    // final linear
    gemm_final_kernel<<<rowBlocks, 256, 0, stream>>>(outbuf, Wl, bl, out);
}

// Round 10
// 337.666 us; speedup vs baseline: 1.2992x; 1.0185x over previous
//
#include <hip/hip_runtime.h>
#include <hip/hip_bf16.h>
#include <hip/hip_fp16.h>
#include <type_traits>

#define Nn 50000
#define RR 3
#define EE 300000

typedef __attribute__((ext_vector_type(8))) short short8;
typedef __attribute__((ext_vector_type(4))) short short4v;
typedef __attribute__((ext_vector_type(4))) float floatx4;

__device__ __forceinline__ short f2bf(float f) {
    __hip_bfloat16 h = __float2bfloat16(f);
    return *reinterpret_cast<short*>(&h);
}
__device__ __forceinline__ float bf2f(short s) {
    __hip_bfloat16 h = *reinterpret_cast<__hip_bfloat16*>(&s);
    return __bfloat162float(h);
}

// ---------------- init: zero counts/totals + W pre-swizzle ----------------

__global__ void init_kernel(const float* __restrict__ W1, const float* __restrict__ W2,
                            short* __restrict__ Z, int* __restrict__ counts,
                            int* __restrict__ totals) {
    int bx = blockIdx.x;
    if (bx < 586) {
        int i = bx * 256 + threadIdx.x;
        if (i < RR * Nn) counts[i] = 0;
        if (i < 4) totals[i] = 0;
    } else {
        int idx = (bx - 586) * 256 + threadIdx.x;   // 2*3*4*8*64 = 12288
        if (idx >= 12288) return;
        int lane = idx & 63;
        int nt = (idx >> 6) & 7;
        int kt = (idx >> 9) & 3;
        int rl = idx >> 11;
        int layer = rl / 3, r = rl % 3;
        const float* W = (layer ? W2 : W1) + (size_t)r * 16384;
        int n = nt * 16 + (lane & 15);
        int k0 = kt * 32 + (lane >> 4) * 8;
        short8 v;
        #pragma unroll
        for (int j = 0; j < 8; ++j) v[j] = f2bf(W[(size_t)(k0 + j) * 128 + n]);
        *(short8*)&Z[(size_t)idx * 8] = v;
    }
}

// ---------------- CSR build ----------------

__global__ void count_kernel(const int* __restrict__ edges, int* __restrict__ counts,
                             int* __restrict__ ord) {
    int i = blockIdx.x * blockDim.x + threadIdx.x;   // RR*EE/8 threads
    if (i >= RR * EE / 8) return;
    int g = i * 8;
    int r = g / EE, e0 = g - r * EE;
    const int* db = &edges[(size_t)r * 2 * EE + EE + e0];
    int4 d0 = *(const int4*)db;
    int4 d1 = *(const int4*)(db + 4);
    int* cb = counts + r * Nn;
    int4 o0, o1;
    o0.x = atomicAdd(&cb[d0.x], 1);
    o0.y = atomicAdd(&cb[d0.y], 1);
    o0.z = atomicAdd(&cb[d0.z], 1);
    o0.w = atomicAdd(&cb[d0.w], 1);
    o1.x = atomicAdd(&cb[d1.x], 1);
    o1.y = atomicAdd(&cb[d1.y], 1);
    o1.z = atomicAdd(&cb[d1.z], 1);
    o1.w = atomicAdd(&cb[d1.w], 1);
    *(int4*)&ord[g] = o0;
    *(int4*)&ord[g + 4] = o1;
}

__global__ __launch_bounds__(256) void alloc_kernel(const int* __restrict__ counts,
                                                    int* __restrict__ row_start,
                                                    int* __restrict__ totals) {
    __shared__ int s[256];
    __shared__ int base_s;
    int r = blockIdx.y;
    int tid = threadIdx.x;
    int n = blockIdx.x * 256 + tid;
    int idx = r * Nn + n;
    int c = (n < Nn) ? counts[idx] : 0;
    s[tid] = c;
    __syncthreads();
    #pragma unroll
    for (int off = 1; off < 256; off <<= 1) {
        int v = 0;
        if (tid >= off) v = s[tid - off];
        __syncthreads();
        if (tid >= off) s[tid] += v;
        __syncthreads();
    }
    if (tid == 255) base_s = atomicAdd(&totals[r], s[255]);
    __syncthreads();
    if (n < Nn) row_start[idx] = base_s + s[tid] - c;
}

__global__ void scatter_kernel(const int* __restrict__ edges, const int* __restrict__ ord,
                               const int* __restrict__ row_start,
                               int* __restrict__ csr_s, int* __restrict__ csr_d) {
    int i = blockIdx.x * blockDim.x + threadIdx.x;
    if (i >= RR * EE / 8) return;
    int g = i * 8;
    int r = g / EE, e0 = g - r * EE;
    const int* sb = &edges[(size_t)r * 2 * EE + e0];
    const int* db = sb + EE;
    int4 s0 = *(const int4*)sb, s1 = *(const int4*)(sb + 4);
    int4 d0 = *(const int4*)db, d1 = *(const int4*)(db + 4);
    int4 o0 = *(const int4*)&ord[g], o1 = *(const int4*)&ord[g + 4];
    const int* rs = row_start + r * Nn;
    int* cs = csr_s + (size_t)r * EE;
    int* cd = csr_d + (size_t)r * EE;
    int p0 = rs[d0.x] + o0.x, p1 = rs[d0.y] + o0.y;
    int p2 = rs[d0.z] + o0.z, p3 = rs[d0.w] + o0.w;
    int p4 = rs[d1.x] + o1.x, p5 = rs[d1.y] + o1.y;
    int p6 = rs[d1.z] + o1.z, p7 = rs[d1.w] + o1.w;
    cs[p0] = s0.x; cs[p1] = s0.y; cs[p2] = s0.z; cs[p3] = s0.w;
    cs[p4] = s1.x; cs[p5] = s1.y; cs[p6] = s1.z; cs[p7] = s1.w;
    cd[p0] = d0.x; cd[p1] = d0.y; cd[p2] = d0.z; cd[p3] = d0.w;
    cd[p4] = d1.x; cd[p5] = d1.y; cd[p6] = d1.z; cd[p7] = d1.w;
}

// ---------------- MFMA GEMM + fused el/er epilogue ----------------
// TA = float (layer 1, x) or short (layer 2, bf16 outbuf with relu pre-applied).

template<typename TA>
__global__ __launch_bounds__(256) void gemm_proj_mfma(const TA* __restrict__ A,
                                                      const short* __restrict__ Z,
                                                      const float* __restrict__ al,
                                                      const float* __restrict__ ar,
                                                      __half* __restrict__ C,
                                                      float* __restrict__ el,
                                                      float* __restrict__ er) {
    __shared__ short A_lds[64 * 136];   // reused as __half[64*136] for the epilogue
    __shared__ float al_lds[384], ar_lds[384];
    int tid = threadIdx.x;
    int row0 = blockIdx.x * 64;
    if (tid < 128) { al_lds[256 + tid] = al[256 + tid]; ar_lds[256 + tid] = ar[256 + tid]; }
    al_lds[tid] = al[tid]; ar_lds[tid] = ar[tid];
    if constexpr (std::is_same<TA, float>::value) {
        #pragma unroll
        for (int p = 0; p < 8; ++p) {
            int f = p * 256 + tid;
            int row = f >> 5;
            int c4 = (f & 31) * 4;
            float4 v = make_float4(0.f, 0.f, 0.f, 0.f);
            if (row0 + row < Nn) v = *(const float4*)&A[(size_t)(row0 + row) * 128 + c4];
            short4v sv;
            sv[0] = f2bf(v.x); sv[1] = f2bf(v.y); sv[2] = f2bf(v.z); sv[3] = f2bf(v.w);
            *(short4v*)&A_lds[row * 136 + c4] = sv;
        }
    } else {
        #pragma unroll
        for (int p = 0; p < 4; ++p) {
            int c = p * 256 + tid;          // 1024 chunks of 8 shorts
            int row = c >> 4, c8 = (c & 15) * 8;
            short8 v = (short8)(0);
            if (row0 + row < Nn) v = *(const short8*)&A[(size_t)(row0 + row) * 128 + c8];
            *(short8*)&A_lds[row * 136 + c8] = v;
        }
    }
    __syncthreads();
    int wave = tid >> 6, lane = tid & 63;
    int m = lane & 15, q = lane >> 4;
    short8 af[4];
    #pragma unroll
    for (int kt = 0; kt < 4; ++kt)
        af[kt] = *(short8*)&A_lds[(wave * 16 + m) * 136 + kt * 32 + q * 8];
    __syncthreads();   // A_lds dead; reuse as epilogue buffer
    __half* lds_h = (__half*)A_lds;
    int row8 = tid >> 2;
    int hh = tid & 3;
    for (int r = 0; r < RR; ++r) {
        floatx4 acc[8];
        #pragma unroll
        for (int nt = 0; nt < 8; ++nt) acc[nt] = (floatx4)(0.f);
        const short* Zr = Z + (size_t)r * 16384;
        #pragma unroll
        for (int kt = 0; kt < 4; ++kt) {
            #pragma unroll
            for (int nt = 0; nt < 8; ++nt) {
                short8 bf = *(const short8*)&Zr[(size_t)(kt * 8 + nt) * 512 + lane * 8];
                acc[nt] = __builtin_amdgcn_mfma_f32_16x16x32_bf16(af[kt], bf, acc[nt], 0, 0, 0);
            }
        }
        #pragma unroll
        for (int nt = 0; nt < 8; ++nt) {
            int col = nt * 16 + m;
            #pragma unroll
            for (int reg = 0; reg < 4; ++reg)
                lds_h[(wave * 16 + q * 4 + reg) * 136 + col] = __float2half(acc[nt][reg]);
        }
        __syncthreads();
        __half* Cr = C + (size_t)r * Nn * 128;
        #pragma unroll
        for (int p = 0; p < 4; ++p) {
            int lin = p * 256 + tid;
            int row = lin >> 4, c8 = (lin & 15) * 8;
            if (row0 + row < Nn)
                *(short8*)&Cr[(size_t)(row0 + row) * 128 + c8] = *(short8*)&lds_h[row * 136 + c8];
        }
        {
            const __half2* fp = (const __half2*)&lds_h[row8 * 136 + hh * 32];
            const float* alp = &al_lds[r * 128 + hh * 32];
            const float* arp = &ar_lds[r * 128 + hh * 32];
            float sl = 0.f, sr = 0.f;
            #pragma unroll
            for (int d = 0; d < 16; ++d) {
                float2 v = __half22float2(fp[d]);
                sl += v.x * alp[2 * d] + v.y * alp[2 * d + 1];
                sr += v.x * arp[2 * d] + v.y * arp[2 * d + 1];
            }
            if (row0 + row8 < Nn) {
                size_t ei = (size_t)(r * Nn + row0 + row8) * 4 + hh;
                el[ei] = sl;
                er[ei] = sr;
            }
        }
        __syncthreads();
    }
}

// ---------------- Final GEMM: A[N,128] @ Wl[128,64] + bl -> out [N,64] fp32 ----------------

__global__ __launch_bounds__(256) void gemm_final_kernel(const float* __restrict__ A,
                                                         const float* __restrict__ Wl,
                                                         const float* __restrict__ bl,
                                                         float* __restrict__ out) {
    __shared__ float As[16][65];
    __shared__ float Bs[16][65];
    int tid = threadIdx.x;
    int row0 = blockIdx.x * 64;
    float acc[4][4] = {};
    int tx = tid & 15, ty = tid >> 4;
    for (int k0 = 0; k0 < 128; k0 += 16) {
        {
            int mm = tid >> 2, c = (tid & 3) * 4;
            int row = row0 + mm;
            float4 v = make_float4(0.f, 0.f, 0.f, 0.f);
            if (row < Nn) v = *(const float4*)&A[(size_t)row * 128 + k0 + c];
            As[c + 0][mm] = v.x; As[c + 1][mm] = v.y; As[c + 2][mm] = v.z; As[c + 3][mm] = v.w;
        }
        {
            int kk = tid >> 4, j = (tid & 15) * 4;
            float4 v = *(const float4*)&Wl[(size_t)(k0 + kk) * 64 + j];
            *(float4*)&Bs[kk][j] = v;
        }
        __syncthreads();
        #pragma unroll
        for (int kk = 0; kk < 16; ++kk) {
            float4 a = *(const float4*)&As[kk][ty * 4];
            float4 b = *(const float4*)&Bs[kk][tx * 4];
            float av[4] = {a.x, a.y, a.z, a.w};
            float bv[4] = {b.x, b.y, b.z, b.w};
            #pragma unroll
            for (int i = 0; i < 4; ++i)
                #pragma unroll
                for (int j = 0; j < 4; ++j) acc[i][j] += av[i] * bv[j];
        }
        __syncthreads();
    }
    float4 bias = *(const float4*)&bl[tx * 4];
    #pragma unroll
    for (int i = 0; i < 4; ++i) {
        int row = row0 + ty * 4 + i;
        if (row >= Nn) continue;
        float4 v = make_float4(acc[i][0] + bias.x, acc[i][1] + bias.y,
                               acc[i][2] + bias.z, acc[i][3] + bias.w);
        *(float4*)&out[(size_t)row * 64 + tx * 4] = v;
    }
}

// ---------------- edge-parallel softmax weights (fp16 out) ----------------

__global__ __launch_bounds__(256) void wexp_kernel(const int* __restrict__ csr_s,
                                                   const int* __restrict__ csr_d,
                                                   const float* __restrict__ el,
                                                   const float* __restrict__ er,
                                                   __half* __restrict__ wq) {
    int r = blockIdx.y;
    int k = blockIdx.x * 256 + threadIdx.x;
    if (k >= EE) return;
    size_t gk = (size_t)r * EE + k;
    int es = csr_s[gk], ed = csr_d[gk];
    float4 l4 = *(const float4*)&el[(size_t)(r * Nn + es) * 4];
    float4 r4 = *(const float4*)&er[(size_t)(r * Nn + ed) * 4];
    float lv[4] = {l4.x, l4.y, l4.z, l4.w};
    float rv[4] = {r4.x, r4.y, r4.z, r4.w};
    #pragma unroll
    for (int h = 0; h < 4; ++h) {
        float x = lv[h] + rv[h];
        x = (x > 0.f) ? x : 0.2f * x;
        wq[(size_t)h * (RR * EE) + gk] = __float2half(__expf(x));
    }
}

// ---------------- aggregation: one wave per dst node; 8-deep gather groups ----------------
// OUT_BF16_RELU: layer-1 variant writes bf16(relu(acc)) for direct layer-2 staging.

template<bool OUT_BF16_RELU>
__global__ __launch_bounds__(256) void agg_kernel(const __half2* __restrict__ feat2,
                                                  const __half* __restrict__ wq,
                                                  const int* __restrict__ csr_s,
                                                  const int* __restrict__ row_start,
                                                  const int* __restrict__ counts,
                                                  const float* __restrict__ b,
                                                  void* __restrict__ out) {
    int wave = threadIdx.x >> 6;
    int lane = threadIdx.x & 63;
    int n = blockIdx.x * 4 + wave;
    if (n >= Nn) return;
    int h = lane >> 4;
    int hl = lane & 15;
    int grp = lane & 48;
    int t2 = lane * 2;
    int cntA[RR], stA[RR], sC[RR];
    float wC[RR];
    #pragma unroll
    for (int r = 0; r < RR; ++r) {
        cntA[r] = counts[r * Nn + n];
        stA[r] = row_start[r * Nn + n];
    }
    #pragma unroll
    for (int r = 0; r < RR; ++r) {
        sC[r] = 0; wC[r] = 0.f;
        if (hl < cntA[r]) {
            int idx = stA[r] + hl;
            sC[r] = csr_s[(size_t)r * EE + idx];
            wC[r] = __half2float(wq[(size_t)h * (RR * EE) + (size_t)r * EE + idx]);
        }
    }
    float accx = b[t2] + b[128 + t2] + b[256 + t2];
    float accy = b[t2 + 1] + b[128 + t2 + 1] + b[256 + t2 + 1];
    #pragma unroll
    for (int r = 0; r < RR; ++r) {
        int cnt = cntA[r];
        if (cnt == 0) continue;
        const __half2* fr = feat2 + (size_t)r * Nn * 64;
        float den = 0.f, numx = 0.f, numy = 0.f;
        int s_l = sC[r];
        float w_l = wC[r];
        int i0 = 0;
        while (true) {
            int mm = cnt - i0; if (mm > 16) mm = 16;
            int mm8 = (mm + 7) & ~7;
            for (int j = 0; j < mm8; j += 8) {
                int s0 = __shfl(s_l, j);
                int s1 = __shfl(s_l, j + 1);
                int s2 = __shfl(s_l, j + 2);
                int s3 = __shfl(s_l, j + 3);
                int s4 = __shfl(s_l, j + 4);
                int s5 = __shfl(s_l, j + 5);
                int s6 = __shfl(s_l, j + 6);
                int s7 = __shfl(s_l, j + 7);
                float w0 = __shfl(w_l, grp | j);
                float w1 = __shfl(w_l, grp | (j + 1));
                float w2 = __shfl(w_l, grp | (j + 2));
                float w3 = __shfl(w_l, grp | (j + 3));
                float w4 = __shfl(w_l, grp | (j + 4));
                float w5 = __shfl(w_l, grp | (j + 5));
                float w6 = __shfl(w_l, grp | (j + 6));
                float w7 = __shfl(w_l, grp | (j + 7));
                __half2 f0 = fr[(size_t)s0 * 64 + lane];
                __half2 f1 = fr[(size_t)s1 * 64 + lane];
                __half2 f2 = fr[(size_t)s2 * 64 + lane];
                __half2 f3 = fr[(size_t)s3 * 64 + lane];
                __half2 f4 = fr[(size_t)s4 * 64 + lane];
                __half2 f5 = fr[(size_t)s5 * 64 + lane];
                __half2 f6 = fr[(size_t)s6 * 64 + lane];
                __half2 f7 = fr[(size_t)s7 * 64 + lane];
                float2 g0 = __half22float2(f0), g1 = __half22float2(f1);
                float2 g2 = __half22float2(f2), g3 = __half22float2(f3);
                float2 g4 = __half22float2(f4), g5 = __half22float2(f5);
                float2 g6 = __half22float2(f6), g7 = __half22float2(f7);
                den += ((w0 + w1) + (w2 + w3)) + ((w4 + w5) + (w6 + w7));
                numx += (w0 * g0.x + w1 * g1.x + w2 * g2.x + w3 * g3.x)
                      + (w4 * g4.x + w5 * g5.x + w6 * g6.x + w7 * g7.x);
                numy += (w0 * g0.y + w1 * g1.y + w2 * g2.y + w3 * g3.y)
                      + (w4 * g4.y + w5 * g5.y + w6 * g6.y + w7 * g7.y);
            }
            i0 += 16;
            if (i0 >= cnt) break;
            s_l = 0; w_l = 0.f;
            if (i0 + hl < cnt) {
                int idx = stA[r] + i0 + hl;
                s_l = csr_s[(size_t)r * EE + idx];
                w_l = __half2float(wq[(size_t)h * (RR * EE) + (size_t)r * EE + idx]);
            }
        }
        float inv = 1.f / den;
        accx += numx * inv;
        accy += numy * inv;
    }
    if constexpr (OUT_BF16_RELU) {
        short* o = (short*)out;
        short2 pk;
        pk.x = f2bf(fmaxf(accx, 0.f));
        pk.y = f2bf(fmaxf(accy, 0.f));
        *(short2*)&o[(size_t)n * 128 + t2] = pk;
    } else {
        float* o = (float*)out;
        *(float2*)&o[(size_t)n * 128 + t2] = make_float2(accx, accy);
    }
}

// ---------------- launch ----------------

extern "C" void kernel_launch(void* const* d_in, const int* in_sizes, int n_in,
                              void* d_out, int out_size, void* d_ws, size_t ws_size,
                              hipStream_t stream) {
    const float* x   = (const float*)d_in[0];
    const int*  edges = (const int*)d_in[1];
    const float* W1  = (const float*)d_in[2];
    const float* al1 = (const float*)d_in[3];
    const float* ar1 = (const float*)d_in[4];
    const float* b1  = (const float*)d_in[5];
    const float* W2  = (const float*)d_in[6];
    const float* al2 = (const float*)d_in[7];
    const float* ar2 = (const float*)d_in[8];
    const float* b2  = (const float*)d_in[9];
    const float* Wl  = (const float*)d_in[10];
    const float* bl  = (const float*)d_in[11];
    float* out = (float*)d_out;

    // workspace layout (~88 MB; ws proven >= 113 MB in R2)
    __half* feat  = (__half*)d_ws;                          // 3*N*128 fp16
    short* Z      = (short*)(feat + (size_t)RR * Nn * 128); // 98304 bf16
    float* el     = (float*)(Z + 98304);                    // 3*N*4
    float* er     = el + (size_t)RR * Nn * 4;               // 3*N*4
    float* outbuf = er + (size_t)RR * Nn * 4;               // N*128 fp32 (layer2) / bf16 (layer1, aliased)
    __half* wq    = (__half*)(outbuf + (size_t)Nn * 128);   // 4 * 3E halfs
    int* counts    = (int*)(wq + (size_t)4 * RR * EE);      // 3*N
    int* row_start = counts + RR * Nn;                      // 3*N
    int* totals    = row_start + RR * Nn;                   // 4
    int* ord       = totals + 4;                            // 3*E
    int* csr_s     = ord + RR * EE;                         // 3*E
    int* csr_d     = csr_s + RR * EE;                       // 3*E
    short* outb16  = (short*)outbuf;                        // layer-1 bf16 view

    const int rowBlocks  = (Nn + 63) / 64;    // 782
    const int nodeBlocks = (Nn + 255) / 256;  // 196
    const int aggBlocks  = (Nn + 3) / 4;      // 12500
    const int edgeBlocks = (EE + 255) / 256;  // 1172
    const int edge8Blocks = (RR * EE / 8 + 255) / 256;  // 440

    // init (zero + wswz) + CSR build
    init_kernel<<<634, 256, 0, stream>>>(W1, W2, Z, counts, totals);
    count_kernel<<<edge8Blocks, 256, 0, stream>>>(edges, counts, ord);
    alloc_kernel<<<dim3(nodeBlocks, RR), 256, 0, stream>>>(counts, row_start, totals);
    scatter_kernel<<<edge8Blocks, 256, 0, stream>>>(edges, ord, row_start, csr_s, csr_d);

    // layer 1 (el/er fused into gemm epilogue; agg writes bf16+relu)
    gemm_proj_mfma<float><<<rowBlocks, 256, 0, stream>>>(x, Z, al1, ar1, feat, el, er);
    wexp_kernel<<<dim3(edgeBlocks, RR), 256, 0, stream>>>(csr_s, csr_d, el, er, wq);
    agg_kernel<true><<<aggBlocks, 256, 0, stream>>>((const __half2*)feat, wq, csr_s, row_start, counts, b1, outb16);

    // layer 2 (bf16 A input, relu already applied)
    gemm_proj_mfma<short><<<rowBlocks, 256, 0, stream>>>(outb16, Z + 49152, al2, ar2, feat, el, er);
    wexp_kernel<<<dim3(edgeBlocks, RR), 256, 0, stream>>>(csr_s, csr_d, el, er, wq);
    agg_kernel<false><<<aggBlocks, 256, 0, stream>>>((const __half2*)feat, wq, csr_s, row_start, counts, b2, outbuf);

    // final linear
    gemm_final_kernel<<<rowBlocks, 256, 0, stream>>>(outbuf, Wl, bl, out);
}

// Round 11
// 331.932 us; speedup vs baseline: 1.3217x; 1.0173x over previous
//
#include <hip/hip_runtime.h>
#include <hip/hip_bf16.h>
#include <hip/hip_fp16.h>
#include <type_traits>

#define Nn 50000
#define RR 3
#define EE 300000

typedef __attribute__((ext_vector_type(8))) short short8;
typedef __attribute__((ext_vector_type(4))) short short4v;
typedef __attribute__((ext_vector_type(4))) float floatx4;

__device__ __forceinline__ short f2bf(float f) {
    __hip_bfloat16 h = __float2bfloat16(f);
    return *reinterpret_cast<short*>(&h);
}

// ---------------- count (8 edges/thread, ordinal out) + fused W pre-swizzle ----------------
// blocks [0, 440): count; blocks [440, 488): wswz. counts pre-zeroed by hipMemsetAsync.

__global__ void count_wswz_kernel(const int* __restrict__ edges, int* __restrict__ counts,
                                  int* __restrict__ ord,
                                  const float* __restrict__ W1, const float* __restrict__ W2,
                                  short* __restrict__ Z) {
    int bx = blockIdx.x;
    if (bx >= 440) {
        int idx = (bx - 440) * 256 + threadIdx.x;   // 2*3*4*8*64 = 12288
        if (idx >= 12288) return;
        int lane = idx & 63;
        int nt = (idx >> 6) & 7;
        int kt = (idx >> 9) & 3;
        int rl = idx >> 11;
        int layer = rl / 3, r = rl % 3;
        const float* W = (layer ? W2 : W1) + (size_t)r * 16384;
        int n = nt * 16 + (lane & 15);
        int k0 = kt * 32 + (lane >> 4) * 8;
        short8 v;
        #pragma unroll
        for (int j = 0; j < 8; ++j) v[j] = f2bf(W[(size_t)(k0 + j) * 128 + n]);
        *(short8*)&Z[(size_t)idx * 8] = v;
        return;
    }
    int i = bx * 256 + threadIdx.x;   // RR*EE/8 threads
    if (i >= RR * EE / 8) return;
    int g = i * 8;
    int r = g / EE, e0 = g - r * EE;
    const int* db = &edges[(size_t)r * 2 * EE + EE + e0];
    int4 d0 = *(const int4*)db;
    int4 d1 = *(const int4*)(db + 4);
    int* cb = counts + r * Nn;
    int4 o0, o1;
    o0.x = atomicAdd(&cb[d0.x], 1);
    o0.y = atomicAdd(&cb[d0.y], 1);
    o0.z = atomicAdd(&cb[d0.z], 1);
    o0.w = atomicAdd(&cb[d0.w], 1);
    o1.x = atomicAdd(&cb[d1.x], 1);
    o1.y = atomicAdd(&cb[d1.y], 1);
    o1.z = atomicAdd(&cb[d1.z], 1);
    o1.w = atomicAdd(&cb[d1.w], 1);
    *(int4*)&ord[g] = o0;
    *(int4*)&ord[g + 4] = o1;
}

__global__ __launch_bounds__(256) void alloc_kernel(const int* __restrict__ counts,
                                                    int* __restrict__ row_start,
                                                    int* __restrict__ totals) {
    __shared__ int s[256];
    __shared__ int base_s;
    int r = blockIdx.y;
    int tid = threadIdx.x;
    int n = blockIdx.x * 256 + tid;
    int idx = r * Nn + n;
    int c = (n < Nn) ? counts[idx] : 0;
    s[tid] = c;
    __syncthreads();
    #pragma unroll
    for (int off = 1; off < 256; off <<= 1) {
        int v = 0;
        if (tid >= off) v = s[tid - off];
        __syncthreads();
        if (tid >= off) s[tid] += v;
        __syncthreads();
    }
    if (tid == 255) base_s = atomicAdd(&totals[r], s[255]);
    __syncthreads();
    if (n < Nn) row_start[idx] = base_s + s[tid] - c;
}

// ---------------- scatter body (called from the fused gemm1 kernel) ----------------

__device__ __forceinline__ void scatter_body(int bid, const int* __restrict__ edges,
                                             const int* __restrict__ ord,
                                             const int* __restrict__ row_start,
                                             int* __restrict__ csr_s, int* __restrict__ csr_d) {
    int i = bid * 256 + threadIdx.x;
    if (i >= RR * EE / 8) return;
    int g = i * 8;
    int r = g / EE, e0 = g - r * EE;
    const int* sb = &edges[(size_t)r * 2 * EE + e0];
    const int* db = sb + EE;
    int4 s0 = *(const int4*)sb, s1 = *(const int4*)(sb + 4);
    int4 d0 = *(const int4*)db, d1 = *(const int4*)(db + 4);
    int4 o0 = *(const int4*)&ord[g], o1 = *(const int4*)&ord[g + 4];
    const int* rs = row_start + r * Nn;
    int* cs = csr_s + (size_t)r * EE;
    int* cd = csr_d + (size_t)r * EE;
    int p0 = rs[d0.x] + o0.x, p1 = rs[d0.y] + o0.y;
    int p2 = rs[d0.z] + o0.z, p3 = rs[d0.w] + o0.w;
    int p4 = rs[d1.x] + o1.x, p5 = rs[d1.y] + o1.y;
    int p6 = rs[d1.z] + o1.z, p7 = rs[d1.w] + o1.w;
    cs[p0] = s0.x; cs[p1] = s0.y; cs[p2] = s0.z; cs[p3] = s0.w;
    cs[p4] = s1.x; cs[p5] = s1.y; cs[p6] = s1.z; cs[p7] = s1.w;
    cd[p0] = d0.x; cd[p1] = d0.y; cd[p2] = d0.z; cd[p3] = d0.w;
    cd[p4] = d1.x; cd[p5] = d1.y; cd[p6] = d1.z; cd[p7] = d1.w;
}

// ---------------- MFMA GEMM + fused el/er epilogue (+ optional fused scatter blocks) ---------
// TA = float (layer 1) or short (layer 2, bf16 relu-applied). FUSE_SCATTER: blocks past
// rowBlocks run scatter instead (block-uniform branch; they return before any barrier).

template<typename TA, bool FUSE_SCATTER>
__global__ __launch_bounds__(256) void gemm_proj_mfma(const TA* __restrict__ A,
                                                      const short* __restrict__ Z,
                                                      const float* __restrict__ al,
                                                      const float* __restrict__ ar,
                                                      __half* __restrict__ C,
                                                      float* __restrict__ el,
                                                      float* __restrict__ er,
                                                      const int* __restrict__ edges,
                                                      const int* __restrict__ ord,
                                                      const int* __restrict__ row_start,
                                                      int* __restrict__ csr_s,
                                                      int* __restrict__ csr_d) {
    const int rowBlocks = (Nn + 63) / 64;   // 782
    if (FUSE_SCATTER && blockIdx.x >= rowBlocks) {
        scatter_body(blockIdx.x - rowBlocks, edges, ord, row_start, csr_s, csr_d);
        return;
    }
    __shared__ short A_lds[64 * 136];   // reused as __half[64*136] for the epilogue
    __shared__ float al_lds[384], ar_lds[384];
    int tid = threadIdx.x;
    int row0 = blockIdx.x * 64;
    if (tid < 128) { al_lds[256 + tid] = al[256 + tid]; ar_lds[256 + tid] = ar[256 + tid]; }
    al_lds[tid] = al[tid]; ar_lds[tid] = ar[tid];
    if constexpr (std::is_same<TA, float>::value) {
        #pragma unroll
        for (int p = 0; p < 8; ++p) {
            int f = p * 256 + tid;
            int row = f >> 5;
            int c4 = (f & 31) * 4;
            float4 v = make_float4(0.f, 0.f, 0.f, 0.f);
            if (row0 + row < Nn) v = *(const float4*)&A[(size_t)(row0 + row) * 128 + c4];
            short4v sv;
            sv[0] = f2bf(v.x); sv[1] = f2bf(v.y); sv[2] = f2bf(v.z); sv[3] = f2bf(v.w);
            *(short4v*)&A_lds[row * 136 + c4] = sv;
        }
    } else {
        #pragma unroll
        for (int p = 0; p < 4; ++p) {
            int c = p * 256 + tid;          // 1024 chunks of 8 shorts
            int row = c >> 4, c8 = (c & 15) * 8;
            short8 v = (short8)(0);
            if (row0 + row < Nn) v = *(const short8*)&A[(size_t)(row0 + row) * 128 + c8];
            *(short8*)&A_lds[row * 136 + c8] = v;
        }
    }
    __syncthreads();
    int wave = tid >> 6, lane = tid & 63;
    int m = lane & 15, q = lane >> 4;
    short8 af[4];
    #pragma unroll
    for (int kt = 0; kt < 4; ++kt)
        af[kt] = *(short8*)&A_lds[(wave * 16 + m) * 136 + kt * 32 + q * 8];
    __syncthreads();   // A_lds dead; reuse as epilogue buffer
    __half* lds_h = (__half*)A_lds;
    int row8 = tid >> 2;
    int hh = tid & 3;
    for (int r = 0; r < RR; ++r) {
        floatx4 acc[8];
        #pragma unroll
        for (int nt = 0; nt < 8; ++nt) acc[nt] = (floatx4)(0.f);
        const short* Zr = Z + (size_t)r * 16384;
        #pragma unroll
        for (int kt = 0; kt < 4; ++kt) {
            #pragma unroll
            for (int nt = 0; nt < 8; ++nt) {
                short8 bf = *(const short8*)&Zr[(size_t)(kt * 8 + nt) * 512 + lane * 8];
                acc[nt] = __builtin_amdgcn_mfma_f32_16x16x32_bf16(af[kt], bf, acc[nt], 0, 0, 0);
            }
        }
        #pragma unroll
        for (int nt = 0; nt < 8; ++nt) {
            int col = nt * 16 + m;
            #pragma unroll
            for (int reg = 0; reg < 4; ++reg)
                lds_h[(wave * 16 + q * 4 + reg) * 136 + col] = __float2half(acc[nt][reg]);
        }
        __syncthreads();
        __half* Cr = C + (size_t)r * Nn * 128;
        #pragma unroll
        for (int p = 0; p < 4; ++p) {
            int lin = p * 256 + tid;
            int row = lin >> 4, c8 = (lin & 15) * 8;
            if (row0 + row < Nn)
                *(short8*)&Cr[(size_t)(row0 + row) * 128 + c8] = *(short8*)&lds_h[row * 136 + c8];
        }
        {
            const __half2* fp = (const __half2*)&lds_h[row8 * 136 + hh * 32];
            const float* alp = &al_lds[r * 128 + hh * 32];
            const float* arp = &ar_lds[r * 128 + hh * 32];
            float sl = 0.f, sr = 0.f;
            #pragma unroll
            for (int d = 0; d < 16; ++d) {
                float2 v = __half22float2(fp[d]);
                sl += v.x * alp[2 * d] + v.y * alp[2 * d + 1];
                sr += v.x * arp[2 * d] + v.y * arp[2 * d + 1];
            }
            if (row0 + row8 < Nn) {
                size_t ei = (size_t)(r * Nn + row0 + row8) * 4 + hh;
                el[ei] = sl;
                er[ei] = sr;
            }
        }
        __syncthreads();
    }
}

// ---------------- Final GEMM: A[N,128] @ Wl[128,64] + bl -> out [N,64] fp32 ----------------

__global__ __launch_bounds__(256) void gemm_final_kernel(const float* __restrict__ A,
                                                         const float* __restrict__ Wl,
                                                         const float* __restrict__ bl,
                                                         float* __restrict__ out) {
    __shared__ float As[16][65];
    __shared__ float Bs[16][65];
    int tid = threadIdx.x;
    int row0 = blockIdx.x * 64;
    float acc[4][4] = {};
    int tx = tid & 15, ty = tid >> 4;
    for (int k0 = 0; k0 < 128; k0 += 16) {
        {
            int mm = tid >> 2, c = (tid & 3) * 4;
            int row = row0 + mm;
            float4 v = make_float4(0.f, 0.f, 0.f, 0.f);
            if (row < Nn) v = *(const float4*)&A[(size_t)row * 128 + k0 + c];
            As[c + 0][mm] = v.x; As[c + 1][mm] = v.y; As[c + 2][mm] = v.z; As[c + 3][mm] = v.w;
        }
        {
            int kk = tid >> 4, j = (tid & 15) * 4;
            float4 v = *(const float4*)&Wl[(size_t)(k0 + kk) * 64 + j];
            *(float4*)&Bs[kk][j] = v;
        }
        __syncthreads();
        #pragma unroll
        for (int kk = 0; kk < 16; ++kk) {
            float4 a = *(const float4*)&As[kk][ty * 4];
            float4 b = *(const float4*)&Bs[kk][tx * 4];
            float av[4] = {a.x, a.y, a.z, a.w};
            float bv[4] = {b.x, b.y, b.z, b.w};
            #pragma unroll
            for (int i = 0; i < 4; ++i)
                #pragma unroll
                for (int j = 0; j < 4; ++j) acc[i][j] += av[i] * bv[j];
        }
        __syncthreads();
    }
    float4 bias = *(const float4*)&bl[tx * 4];
    #pragma unroll
    for (int i = 0; i < 4; ++i) {
        int row = row0 + ty * 4 + i;
        if (row >= Nn) continue;
        float4 v = make_float4(acc[i][0] + bias.x, acc[i][1] + bias.y,
                               acc[i][2] + bias.z, acc[i][3] + bias.w);
        *(float4*)&out[(size_t)row * 64 + tx * 4] = v;
    }
}

// ---------------- edge-parallel softmax weights (fp16 out) ----------------

__global__ __launch_bounds__(256) void wexp_kernel(const int* __restrict__ csr_s,
                                                   const int* __restrict__ csr_d,
                                                   const float* __restrict__ el,
                                                   const float* __restrict__ er,
                                                   __half* __restrict__ wq) {
    int r = blockIdx.y;
    int k = blockIdx.x * 256 + threadIdx.x;
    if (k >= EE) return;
    size_t gk = (size_t)r * EE + k;
    int es = csr_s[gk], ed = csr_d[gk];
    float4 l4 = *(const float4*)&el[(size_t)(r * Nn + es) * 4];
    float4 r4 = *(const float4*)&er[(size_t)(r * Nn + ed) * 4];
    float lv[4] = {l4.x, l4.y, l4.z, l4.w};
    float rv[4] = {r4.x, r4.y, r4.z, r4.w};
    #pragma unroll
    for (int h = 0; h < 4; ++h) {
        float x = lv[h] + rv[h];
        x = (x > 0.f) ? x : 0.2f * x;
        wq[(size_t)h * (RR * EE) + gk] = __float2half(__expf(x));
    }
}

// ---------------- aggregation: one wave per dst node; 8-deep gather groups ----------------

template<bool OUT_BF16_RELU>
__global__ __launch_bounds__(256) void agg_kernel(const __half2* __restrict__ feat2,
                                                  const __half* __restrict__ wq,
                                                  const int* __restrict__ csr_s,
                                                  const int* __restrict__ row_start,
                                                  const int* __restrict__ counts,
                                                  const float* __restrict__ b,
                                                  void* __restrict__ out) {
    int wave = threadIdx.x >> 6;
    int lane = threadIdx.x & 63;
    int n = blockIdx.x * 4 + wave;
    if (n >= Nn) return;
    int h = lane >> 4;
    int hl = lane & 15;
    int grp = lane & 48;
    int t2 = lane * 2;
    int cntA[RR], stA[RR], sC[RR];
    float wC[RR];
    #pragma unroll
    for (int r = 0; r < RR; ++r) {
        cntA[r] = counts[r * Nn + n];
        stA[r] = row_start[r * Nn + n];
    }
    #pragma unroll
    for (int r = 0; r < RR; ++r) {
        sC[r] = 0; wC[r] = 0.f;
        if (hl < cntA[r]) {
            int idx = stA[r] + hl;
            sC[r] = csr_s[(size_t)r * EE + idx];
            wC[r] = __half2float(wq[(size_t)h * (RR * EE) + (size_t)r * EE + idx]);
        }
    }
    float accx = b[t2] + b[128 + t2] + b[256 + t2];
    float accy = b[t2 + 1] + b[128 + t2 + 1] + b[256 + t2 + 1];
    #pragma unroll
    for (int r = 0; r < RR; ++r) {
        int cnt = cntA[r];
        if (cnt == 0) continue;
        const __half2* fr = feat2 + (size_t)r * Nn * 64;
        float den = 0.f, numx = 0.f, numy = 0.f;
        int s_l = sC[r];
        float w_l = wC[r];
        int i0 = 0;
        while (true) {
            int mm = cnt - i0; if (mm > 16) mm = 16;
            int mm8 = (mm + 7) & ~7;
            for (int j = 0; j < mm8; j += 8) {
                int s0 = __shfl(s_l, j);
                int s1 = __shfl(s_l, j + 1);
                int s2 = __shfl(s_l, j + 2);
                int s3 = __shfl(s_l, j + 3);
                int s4 = __shfl(s_l, j + 4);
                int s5 = __shfl(s_l, j + 5);
                int s6 = __shfl(s_l, j + 6);
                int s7 = __shfl(s_l, j + 7);
                float w0 = __shfl(w_l, grp | j);
                float w1 = __shfl(w_l, grp | (j + 1));
                float w2 = __shfl(w_l, grp | (j + 2));
                float w3 = __shfl(w_l, grp | (j + 3));
                float w4 = __shfl(w_l, grp | (j + 4));
                float w5 = __shfl(w_l, grp | (j + 5));
                float w6 = __shfl(w_l, grp | (j + 6));
                float w7 = __shfl(w_l, grp | (j + 7));
                __half2 f0 = fr[(size_t)s0 * 64 + lane];
                __half2 f1 = fr[(size_t)s1 * 64 + lane];
                __half2 f2 = fr[(size_t)s2 * 64 + lane];
                __half2 f3 = fr[(size_t)s3 * 64 + lane];
                __half2 f4 = fr[(size_t)s4 * 64 + lane];
                __half2 f5 = fr[(size_t)s5 * 64 + lane];
                __half2 f6 = fr[(size_t)s6 * 64 + lane];
                __half2 f7 = fr[(size_t)s7 * 64 + lane];
                float2 g0 = __half22float2(f0), g1 = __half22float2(f1);
                float2 g2 = __half22float2(f2), g3 = __half22float2(f3);
                float2 g4 = __half22float2(f4), g5 = __half22float2(f5);
                float2 g6 = __half22float2(f6), g7 = __half22float2(f7);
                den += ((w0 + w1) + (w2 + w3)) + ((w4 + w5) + (w6 + w7));
                numx += (w0 * g0.x + w1 * g1.x + w2 * g2.x + w3 * g3.x)
                      + (w4 * g4.x + w5 * g5.x + w6 * g6.x + w7 * g7.x);
                numy += (w0 * g0.y + w1 * g1.y + w2 * g2.y + w3 * g3.y)
                      + (w4 * g4.y + w5 * g5.y + w6 * g6.y + w7 * g7.y);
            }
            i0 += 16;
            if (i0 >= cnt) break;
            s_l = 0; w_l = 0.f;
            if (i0 + hl < cnt) {
                int idx = stA[r] + i0 + hl;
                s_l = csr_s[(size_t)r * EE + idx];
                w_l = __half2float(wq[(size_t)h * (RR * EE) + (size_t)r * EE + idx]);
            }
        }
        float inv = 1.f / den;
        accx += numx * inv;
        accy += numy * inv;
    }
    if constexpr (OUT_BF16_RELU) {
        short* o = (short*)out;
        short2 pk;
        pk.x = f2bf(fmaxf(accx, 0.f));
        pk.y = f2bf(fmaxf(accy, 0.f));
        *(short2*)&o[(size_t)n * 128 + t2] = pk;
    } else {
        float* o = (float*)out;
        *(float2*)&o[(size_t)n * 128 + t2] = make_float2(accx, accy);
    }
}

// ---------------- launch ----------------

extern "C" void kernel_launch(void* const* d_in, const int* in_sizes, int n_in,
                              void* d_out, int out_size, void* d_ws, size_t ws_size,
                              hipStream_t stream) {
    const float* x   = (const float*)d_in[0];
    const int*  edges = (const int*)d_in[1];
    const float* W1  = (const float*)d_in[2];
    const float* al1 = (const float*)d_in[3];
    const float* ar1 = (const float*)d_in[4];
    const float* b1  = (const float*)d_in[5];
    const float* W2  = (const float*)d_in[6];
    const float* al2 = (const float*)d_in[7];
    const float* ar2 = (const float*)d_in[8];
    const float* b2  = (const float*)d_in[9];
    const float* Wl  = (const float*)d_in[10];
    const float* bl  = (const float*)d_in[11];
    float* out = (float*)d_out;

    // workspace layout (~88 MB; ws proven >= 113 MB in R2)
    __half* feat  = (__half*)d_ws;                          // 3*N*128 fp16
    short* Z      = (short*)(feat + (size_t)RR * Nn * 128); // 98304 bf16
    float* el     = (float*)(Z + 98304);                    // 3*N*4
    float* er     = el + (size_t)RR * Nn * 4;               // 3*N*4
    float* outbuf = er + (size_t)RR * Nn * 4;               // N*128 fp32 (l2) / bf16 (l1)
    __half* wq    = (__half*)(outbuf + (size_t)Nn * 128);   // 4 * 3E halfs
    int* counts    = (int*)(wq + (size_t)4 * RR * EE);      // 3*N   (contiguous with totals
    int* totals    = counts + RR * Nn;                      // 4      for single memset)
    int* row_start = totals + 4;                            // 3*N
    int* ord       = row_start + RR * Nn;                   // 3*E
    int* csr_s     = ord + RR * EE;                         // 3*E
    int* csr_d     = csr_s + RR * EE;                       // 3*E
    short* outb16  = (short*)outbuf;                        // layer-1 bf16 view

    const int rowBlocks  = (Nn + 63) / 64;    // 782
    const int nodeBlocks = (Nn + 255) / 256;  // 196
    const int aggBlocks  = (Nn + 3) / 4;      // 12500
    const int edgeBlocks = (EE + 255) / 256;  // 1172
    const int edge8Blocks = (RR * EE / 8 + 255) / 256;  // 440

    // CSR build: memset zeroes counts+totals; wswz hides under count; scatter hides under gemm1
    hipMemsetAsync(counts, 0, (size_t)(RR * Nn + 4) * sizeof(int), stream);
    count_wswz_kernel<<<440 + 48, 256, 0, stream>>>(edges, counts, ord, W1, W2, Z);
    alloc_kernel<<<dim3(nodeBlocks, RR), 256, 0, stream>>>(counts, row_start, totals);

    // layer 1 (el/er fused into gemm epilogue; scatter fused as extra blocks)
    gemm_proj_mfma<float, true><<<rowBlocks + edge8Blocks, 256, 0, stream>>>(
        x, Z, al1, ar1, feat, el, er, edges, ord, row_start, csr_s, csr_d);
    wexp_kernel<<<dim3(edgeBlocks, RR), 256, 0, stream>>>(csr_s, csr_d, el, er, wq);
    agg_kernel<true><<<aggBlocks, 256, 0, stream>>>((const __half2*)feat, wq, csr_s, row_start, counts, b1, outb16);

    // layer 2 (bf16 A input, relu already applied)
    gemm_proj_mfma<short, false><<<rowBlocks, 256, 0, stream>>>(
        outb16, Z + 49152, al2, ar2, feat, el, er, nullptr, nullptr, nullptr, nullptr, nullptr);
    wexp_kernel<<<dim3(edgeBlocks, RR), 256, 0, stream>>>(csr_s, csr_d, el, er, wq);
    agg_kernel<false><<<aggBlocks, 256, 0, stream>>>((const __half2*)feat, wq, csr_s, row_start, counts, b2, outbuf);

    // final linear
    gemm_final_kernel<<<rowBlocks, 256, 0, stream>>>(outbuf, Wl, bl, out);
}